// Round 7
// baseline (225.150 us; speedup 1.0000x reference)
//
#include <hip/hip_runtime.h>
#include <math.h>

#define NPTS  131072
#define NSB   8            // setup blocks (4 clusters each)
#define NPRB  256          // pair blocks (4 pairs each)
#define NPTB  512          // point blocks (256 points each)
#define GRID  (NSB + NPRB + NPTB)
#define DLOG2PIF 58.8120661f
#define DLOG2PI  58.81206612467475
#define SHIFT 92.0f
#define NEGHALF_LOG2E -0.72134752044f
#define LOG2E 1.44269504089f

typedef __attribute__((ext_vector_type(8)))  short short8;
typedef __attribute__((ext_vector_type(16))) float f32x16;

static __device__ __forceinline__ unsigned bfh(float f) {    // fp32 -> bf16 bits (RNE)
  unsigned u = __float_as_uint(f);
  return (u + 0x7FFFu + ((u >> 16) & 1u)) >> 16;
}
static __device__ __forceinline__ float bfhf(float f) {
  return __uint_as_float(bfh(f) << 16);
}
static __device__ __forceinline__ void lse_merge(double& m, double& s, double m2, double s2) {
  if (m2 > m) { s = s*exp(m-m2) + s2; m = m2; }
  else        { s = s + s2*exp(m2-m); }
}

// one kernel, three block roles + fused final; flags[0]=setup-done, flags[1]=ticket
__global__ __launch_bounds__(256) void mega_kernel(
    const float* __restrict__ X, const float* __restrict__ means,
    const float* __restrict__ chols, const float* __restrict__ wts,
    uint4* __restrict__ Afrag, float* __restrict__ Kc, float* __restrict__ Sg,
    double* __restrict__ pairv, double* __restrict__ partials,
    unsigned* __restrict__ flags, float* __restrict__ out)
{
  __shared__ __align__(16) char smem[33792];
  __shared__ double redm[4], reds[4], rtm[4], rts[4], rzm[4], rzs[4];
  __shared__ unsigned lastFlag;
  const int tid = threadIdx.x, wv = tid >> 6, lane = tid & 63;
  const int r = lane & 31, h = lane >> 5;
  const int blk = blockIdx.x;

  if (blk < NSB) {
    // ================= setup role: cluster k = blk*4 + wv =================
    float* Ssh = (float*)smem + wv*1056;
    float* bls = (float*)smem + 4224 + wv*1056;
    const int k = blk*4 + wv;
    const float* cp = chols + (size_t)k*1024 + r*32;
    float4 fa = *(const float4*)(cp + h*8);
    float4 fb = *(const float4*)(cp + h*8 + 4);
    float4 fc = *(const float4*)(cp + 16 + h*8);
    float4 fd = *(const float4*)(cp + 16 + h*8 + 4);
    float v0[8] = {fa.x,fa.y,fa.z,fa.w,fb.x,fb.y,fb.z,fb.w};
    float v1[8] = {fc.x,fc.y,fc.z,fc.w,fd.x,fd.y,fd.z,fd.w};
    short8 hi0, hi1, lo0, lo1;
    #pragma unroll
    for (int j = 0; j < 8; j++) {
      hi0[j] = (short)bfh(v0[j]);  lo0[j] = (short)bfh(v0[j] - bfhf(v0[j]));
      hi1[j] = (short)bfh(v1[j]);  lo1[j] = (short)bfh(v1[j] - bfhf(v1[j]));
    }
    f32x16 acc = {};
    acc = __builtin_amdgcn_mfma_f32_32x32x16_bf16(hi0, hi0, acc, 0,0,0);
    acc = __builtin_amdgcn_mfma_f32_32x32x16_bf16(hi1, hi1, acc, 0,0,0);
    acc = __builtin_amdgcn_mfma_f32_32x32x16_bf16(hi0, lo0, acc, 0,0,0);
    acc = __builtin_amdgcn_mfma_f32_32x32x16_bf16(hi1, lo1, acc, 0,0,0);
    acc = __builtin_amdgcn_mfma_f32_32x32x16_bf16(lo0, hi0, acc, 0,0,0);
    acc = __builtin_amdgcn_mfma_f32_32x32x16_bf16(lo1, hi1, acc, 0,0,0);
    #pragma unroll
    for (int q = 0; q < 16; q++) {
      int row = (q & 3) + 8*(q >> 2) + 4*h;
      Ssh[row*33 + r] = acc[q] + ((row == r) ? 1.0f : 0.0f);
    }
    float a[32];
    #pragma unroll
    for (int j = 0; j < 32; j++) a[j] = Ssh[r*33 + j];
    float ldsum = 0.0f;
    #pragma unroll
    for (int j = 0; j < 32; j++) {
      float dd = __shfl(a[j], j);
      float sq = sqrtf(dd);
      float inv = 1.0f / sq;
      ldsum += __logf(sq);
      float l = a[j] * inv;
      #pragma unroll
      for (int e = j+1; e < 32; e++) {
        float le = __shfl(l, e);
        a[e] = (r >= e) ? fmaf(-l, le, a[e]) : a[e];
      }
      a[j] = (r == j) ? sq : ((r > j) ? l : a[j]);
    }
    #pragma unroll
    for (int j = 0; j < 32; j++) Ssh[r*33 + j] = a[j];
    #pragma unroll 1
    for (int d = 0; d < 32; d++) {        // lane r computes column r of B = L^-1
      float s = (d == r) ? 1.0f : 0.0f;
      for (int j = 0; j < d; j++) s = fmaf(-Ssh[d*33 + j], bls[j*33 + r], s);
      bls[d*33 + r] = s / Ssh[d*33 + d];
    }
    float t0[8], t1[8];
    #pragma unroll
    for (int j = 0; j < 8; j++) {
      t0[j] = bls[r*33 + h*8 + j];
      t1[j] = bls[r*33 + 16 + h*8 + j];
    }
    uint4 s0 = make_uint4(bfh(t0[0])|(bfh(t0[1])<<16), bfh(t0[2])|(bfh(t0[3])<<16),
                          bfh(t0[4])|(bfh(t0[5])<<16), bfh(t0[6])|(bfh(t0[7])<<16));
    uint4 s1 = make_uint4(bfh(t1[0])|(bfh(t1[1])<<16), bfh(t1[2])|(bfh(t1[3])<<16),
                          bfh(t1[4])|(bfh(t1[5])<<16), bfh(t1[6])|(bfh(t1[7])<<16));
    float cvp = 0.0f;
    #pragma unroll
    for (int j = 0; j < 8; j++) {
      cvp = fmaf(t0[j], means[k*32 + h*8 + j], cvp);
      cvp = fmaf(t1[j], means[k*32 + 16 + h*8 + j], cvp);
    }
    float cv = cvp + __shfl_xor(cvp, 32);
    unsigned ch = bfh(cv) ^ 0x8000u;
    unsigned cl = bfh(cv - bfhf(cv)) ^ 0x8000u;
    uint4 s2 = make_uint4((h == 0) ? (ch | (cl<<16)) : 0u, 0u, 0u, 0u);
    Afrag[(k*3 + 0)*64 + lane] = s0;
    Afrag[(k*3 + 1)*64 + lane] = s1;
    Afrag[(k*3 + 2)*64 + lane] = s2;
    if (lane == 0) {
      float wk = wts[k];
      float ld2 = 2.0f*ldsum + DLOG2PIF;
      Kc[k] = LOG2E*(SHIFT - 0.5f*ld2) + log2f(fabsf(wk));
      Sg[k] = (wk < 0.0f) ? -1.0f : 1.0f;
    }
    __syncthreads();
    __threadfence();
    if (tid == 0) atomicAdd(&flags[0], 1u);    // release Afrag/Kc/Sg
  } else if (blk < NSB + NPRB) {
    // ================= pair role: pid = (blk-NSB)*4 + wv ==================
    float* Ssh = (float*)smem + wv*1056;
    const int pid = (blk - NSB)*4 + wv, pi = pid >> 5, pj = pid & 31;
    const float* cpi = chols + (size_t)pi*1024 + r*32;
    const float* cpj = chols + (size_t)pj*1024 + r*32;
    float4 ia = *(const float4*)(cpi + h*8);
    float4 ib = *(const float4*)(cpi + h*8 + 4);
    float4 ic = *(const float4*)(cpi + 16 + h*8);
    float4 id = *(const float4*)(cpi + 16 + h*8 + 4);
    float4 ja = *(const float4*)(cpj + h*8);
    float4 jb = *(const float4*)(cpj + h*8 + 4);
    float4 jc = *(const float4*)(cpj + 16 + h*8);
    float4 jd = *(const float4*)(cpj + 16 + h*8 + 4);
    float vi0[8] = {ia.x,ia.y,ia.z,ia.w,ib.x,ib.y,ib.z,ib.w};
    float vi1[8] = {ic.x,ic.y,ic.z,ic.w,id.x,id.y,id.z,id.w};
    float vj0[8] = {ja.x,ja.y,ja.z,ja.w,jb.x,jb.y,jb.z,jb.w};
    float vj1[8] = {jc.x,jc.y,jc.z,jc.w,jd.x,jd.y,jd.z,jd.w};
    short8 I0h,I0l,I1h,I1l,J0h,J0l,J1h,J1l;
    #pragma unroll
    for (int j = 0; j < 8; j++) {
      I0h[j]=(short)bfh(vi0[j]); I0l[j]=(short)bfh(vi0[j]-bfhf(vi0[j]));
      I1h[j]=(short)bfh(vi1[j]); I1l[j]=(short)bfh(vi1[j]-bfhf(vi1[j]));
      J0h[j]=(short)bfh(vj0[j]); J0l[j]=(short)bfh(vj0[j]-bfhf(vj0[j]));
      J1h[j]=(short)bfh(vj1[j]); J1l[j]=(short)bfh(vj1[j]-bfhf(vj1[j]));
    }
    f32x16 acc = {};
    acc = __builtin_amdgcn_mfma_f32_32x32x16_bf16(I0h, I0h, acc, 0,0,0);
    acc = __builtin_amdgcn_mfma_f32_32x32x16_bf16(I1h, I1h, acc, 0,0,0);
    acc = __builtin_amdgcn_mfma_f32_32x32x16_bf16(I0h, I0l, acc, 0,0,0);
    acc = __builtin_amdgcn_mfma_f32_32x32x16_bf16(I1h, I1l, acc, 0,0,0);
    acc = __builtin_amdgcn_mfma_f32_32x32x16_bf16(I0l, I0h, acc, 0,0,0);
    acc = __builtin_amdgcn_mfma_f32_32x32x16_bf16(I1l, I1h, acc, 0,0,0);
    acc = __builtin_amdgcn_mfma_f32_32x32x16_bf16(J0h, J0h, acc, 0,0,0);
    acc = __builtin_amdgcn_mfma_f32_32x32x16_bf16(J1h, J1h, acc, 0,0,0);
    acc = __builtin_amdgcn_mfma_f32_32x32x16_bf16(J0h, J0l, acc, 0,0,0);
    acc = __builtin_amdgcn_mfma_f32_32x32x16_bf16(J1h, J1l, acc, 0,0,0);
    acc = __builtin_amdgcn_mfma_f32_32x32x16_bf16(J0l, J0h, acc, 0,0,0);
    acc = __builtin_amdgcn_mfma_f32_32x32x16_bf16(J1l, J1h, acc, 0,0,0);
    #pragma unroll
    for (int q = 0; q < 16; q++) {
      int row = (q & 3) + 8*(q >> 2) + 4*h;
      Ssh[row*33 + r] = acc[q] + ((row == r) ? 2.0f : 0.0f);   // +I from each Sigma
    }
    float a[32];
    #pragma unroll
    for (int j = 0; j < 32; j++) a[j] = Ssh[r*33 + j];
    #pragma unroll
    for (int j = 0; j < 32; j++) {
      float dd = __shfl(a[j], j);
      float sq = sqrtf(dd);
      float inv = 1.0f / sq;
      float l = a[j] * inv;
      #pragma unroll
      for (int e = j+1; e < 32; e++) {
        float le = __shfl(l, e);
        a[e] = (r >= e) ? fmaf(-l, le, a[e]) : a[e];
      }
      a[j] = (r == j) ? sq : ((r > j) ? l : a[j]);
    }
    float acc2 = means[pi*32 + r] - means[pj*32 + r];
    float maha = 0.0f, ldsum = 0.0f;
    #pragma unroll
    for (int d = 0; d < 32; d++) {
      float dd = __shfl(a[d], d);
      float yd = __shfl(acc2, d) / dd;
      maha = fmaf(yd, yd, maha);
      ldsum += __logf(dd);
      acc2 = (r > d) ? fmaf(-a[d], yd, acc2) : acc2;
    }
    if (lane == 0) pairv[pid] = -0.5 * ((double)maha + 2.0*(double)ldsum + DLOG2PI);
  } else {
    // ================= point role: 256 points/block =======================
    uint4* fsh  = (uint4*)smem;                       // 1536 uint4 = 24576 B
    float* K2sh = (float*)(smem + 24576);
    float* sksh = (float*)(smem + 24576 + 128);
    const int b = blk - NSB - NPRB;
    const int n0 = b*256 + wv*32 + r;
    short8 xh00, xh01, xh10, xh11, x2c;
    {
      const float* xp0 = X + (size_t)n0*32 + h*8;
      const float* xp1 = X + (size_t)(n0+128)*32 + h*8;
      float4 fa = *(const float4*)(xp0);
      float4 fb = *(const float4*)(xp0 + 4);
      float4 fc = *(const float4*)(xp0 + 16);
      float4 fd = *(const float4*)(xp0 + 20);
      float4 ga = *(const float4*)(xp1);
      float4 gb = *(const float4*)(xp1 + 4);
      float4 gc = *(const float4*)(xp1 + 16);
      float4 gd = *(const float4*)(xp1 + 20);
      float v00[8] = {fa.x,fa.y,fa.z,fa.w,fb.x,fb.y,fb.z,fb.w};
      float v01[8] = {fc.x,fc.y,fc.z,fc.w,fd.x,fd.y,fd.z,fd.w};
      float v10[8] = {ga.x,ga.y,ga.z,ga.w,gb.x,gb.y,gb.z,gb.w};
      float v11[8] = {gc.x,gc.y,gc.z,gc.w,gd.x,gd.y,gd.z,gd.w};
      #pragma unroll
      for (int j = 0; j < 8; j++) {
        xh00[j] = (short)bfh(v00[j]);  xh01[j] = (short)bfh(v01[j]);
        xh10[j] = (short)bfh(v10[j]);  xh11[j] = (short)bfh(v11[j]);
        x2c[j] = 0;
      }
      if (h == 0) { x2c[0] = (short)0x3F80; x2c[1] = (short)0x3F80; }
    }
    // wait for setup (X load/convert already done above, overlapping it)
    if (tid == 0) {
      while (__hip_atomic_load(flags, __ATOMIC_ACQUIRE, __HIP_MEMORY_SCOPE_AGENT) < NSB)
        __builtin_amdgcn_s_sleep(8);
    }
    __syncthreads();
    __threadfence();                                  // acquire: invalidate caches
    if (tid < 32) { K2sh[tid] = Kc[tid]; sksh[tid] = Sg[tid]; }
    float sF0 = 0.0f, sF1 = 0.0f;
    #pragma unroll 1
    for (int ph = 0; ph < 4; ph++) {
      __syncthreads();
      const uint4* src = Afrag + ph*1536;
      #pragma unroll
      for (int t = tid; t < 1536; t += 256) fsh[t] = src[t];
      __syncthreads();
      #pragma unroll 2
      for (int kk = 0; kk < 8; kk++) {
        const short8* fp = (const short8*)(fsh + kk*192);
        short8 a0 = fp[lane], a1 = fp[64+lane], a2 = fp[128+lane];
        const int kidx = ph*8 + kk;
        const float Kk = K2sh[kidx], sk = sksh[kidx];
        f32x16 acc0 = {}, acc1 = {};
        acc0 = __builtin_amdgcn_mfma_f32_32x32x16_bf16(a0, xh00, acc0, 0,0,0);
        acc0 = __builtin_amdgcn_mfma_f32_32x32x16_bf16(a1, xh01, acc0, 0,0,0);
        acc0 = __builtin_amdgcn_mfma_f32_32x32x16_bf16(a2, x2c,  acc0, 0,0,0);
        acc1 = __builtin_amdgcn_mfma_f32_32x32x16_bf16(a0, xh10, acc1, 0,0,0);
        acc1 = __builtin_amdgcn_mfma_f32_32x32x16_bf16(a1, xh11, acc1, 0,0,0);
        acc1 = __builtin_amdgcn_mfma_f32_32x32x16_bf16(a2, x2c,  acc1, 0,0,0);
        float m0a=0.f, m0b=0.f, m1a=0.f, m1b=0.f;
        #pragma unroll
        for (int q = 0; q < 8; q++) {
          m0a = fmaf(acc0[q],   acc0[q],   m0a);
          m0b = fmaf(acc0[q+8], acc0[q+8], m0b);
          m1a = fmaf(acc1[q],   acc1[q],   m1a);
          m1b = fmaf(acc1[q+8], acc1[q+8], m1b);
        }
        float m0 = m0a + m0b, m1 = m1a + m1b;
        m0 += __shfl_xor(m0, 32);
        m1 += __shfl_xor(m1, 32);
        sF0 = fmaf(sk, exp2f(fmaf(m0, NEGHALF_LOG2E, Kk)), sF0);
        sF1 = fmaf(sk, exp2f(fmaf(m1, NEGHALF_LOG2E, Kk)), sF1);
      }
    }
    double vm = -1e300, vs = 0.0;
    if (sF0 != 0.0f) lse_merge(vm, vs, 2.0*log(fabs((double)sF0)) - 2.0*(double)SHIFT, 1.0);
    if (sF1 != 0.0f) lse_merge(vm, vs, 2.0*log(fabs((double)sF1)) - 2.0*(double)SHIFT, 1.0);
    if (lane >= 32) { vm = -1e300; vs = 0.0; }        // upper halves duplicate
    #pragma unroll
    for (int off = 32; off > 0; off >>= 1) {
      double m2 = __shfl_down(vm, off);
      double s2 = __shfl_down(vs, off);
      lse_merge(vm, vs, m2, s2);
    }
    if (lane == 0) { redm[wv] = vm; reds[wv] = vs; }
    __syncthreads();
    if (tid == 0) {
      for (int w = 1; w < 4; w++) lse_merge(vm, vs, redm[w], reds[w]);
      partials[2*b]   = vm;
      partials[2*b+1] = vs;
    }
  }
  // ================= common tail: ticket + fused final ====================
  __syncthreads();
  if (tid == 0) {
    __threadfence();
    lastFlag = (atomicAdd(&flags[1], 1u) == GRID - 1) ? 1u : 0u;
  }
  __syncthreads();
  if (lastFlag) {
    __threadfence();
    double tm = -1e300, ts = 0.0;
    for (int p = tid; p < NPTB; p += 256) lse_merge(tm, ts, partials[2*p], partials[2*p+1]);
    double zm = -1e300, zs = 0.0;
    for (int p = tid; p < 1024; p += 256) {
      int i = p >> 5, j = p & 31;
      lse_merge(zm, zs, pairv[p], (double)wts[i] * (double)wts[j]);
    }
    #pragma unroll
    for (int off = 32; off > 0; off >>= 1) {
      double a2 = __shfl_down(tm, off), b2 = __shfl_down(ts, off);
      lse_merge(tm, ts, a2, b2);
      double c2 = __shfl_down(zm, off), d2 = __shfl_down(zs, off);
      lse_merge(zm, zs, c2, d2);
    }
    if (lane == 0) { rtm[wv]=tm; rts[wv]=ts; rzm[wv]=zm; rzs[wv]=zs; }
    __syncthreads();
    if (tid == 0) {
      for (int w = 1; w < 4; w++) { lse_merge(tm, ts, rtm[w], rts[w]); lse_merge(zm, zs, rzm[w], rzs[w]); }
      double logT = tm + log(ts);
      double logz = zm + log(zs);
      out[0] = (float)((logz - logT) / (double)NPTS);
    }
  }
}

extern "C" void kernel_launch(void* const* d_in, const int* in_sizes, int n_in,
                              void* d_out, int out_size, void* d_ws, size_t ws_size,
                              hipStream_t stream) {
  const float* X     = (const float*)d_in[0];
  const float* means = (const float*)d_in[1];
  const float* chols = (const float*)d_in[2];
  const float* wts   = (const float*)d_in[3];
  float* out = (float*)d_out;
  char* ws = (char*)d_ws;
  uint4*    Afrag    = (uint4*)ws;                // 32*3*64*16 = 98304
  float*    Kc       = (float*)(ws + 98304);      // 128   -> 98432
  float*    Sg       = (float*)(ws + 98432);      // 128   -> 98560
  double*   pairv    = (double*)(ws + 98560);     // 8192  -> 106752
  double*   partials = (double*)(ws + 106752);    // 8192  -> 114944
  unsigned* flags    = (unsigned*)(ws + 114944);  // 8     -> 114952

  hipMemsetAsync(flags, 0, 8, stream);
  mega_kernel<<<GRID, 256, 0, stream>>>(X, means, chols, wts, Afrag, Kc, Sg,
                                        pairv, partials, flags, out);
}

// Round 8
// 152.417 us; speedup vs baseline: 1.4772x; 1.4772x over previous
//
#include <hip/hip_runtime.h>
#include <math.h>

#define NPTS  131072
#define NWB   1024         // work blocks: 256 thr = 4 waves, 1 point-set (32 pts) each
#define DLOG2PIF 58.8120661f
#define DLOG2PI  58.81206612467475
#define SHIFT 92.0f
#define NEGHALF_LOG2E -0.72134752044f
#define LOG2E 1.44269504089f

typedef __attribute__((ext_vector_type(8)))  short short8;
typedef __attribute__((ext_vector_type(16))) float f32x16;

static __device__ __forceinline__ unsigned bfh(float f) {    // fp32 -> bf16 bits (RNE)
  unsigned u = __float_as_uint(f);
  return (u + 0x7FFFu + ((u >> 16) & 1u)) >> 16;
}
static __device__ __forceinline__ float bfhf(float f) {
  return __uint_as_float(bfh(f) << 16);
}
static __device__ __forceinline__ void lse_merge(double& m, double& s, double m2, double s2) {
  if (m2 > m) { s = s*exp(m-m2) + s2; m = m2; }
  else        { s = s + s2*exp(m2-m); }
}

// ===== setup: 8 blocks x 256 thr; wave wv handles cluster blockIdx*4+wv ============
// (r6-validated path, minus the SigmaF global write; zeroes the work ticket)
__global__ __launch_bounds__(256) void setup_kernel(
    const float* __restrict__ means, const float* __restrict__ chols,
    const float* __restrict__ wts,
    uint4* __restrict__ Afrag, float* __restrict__ Kc, float* __restrict__ Sg,
    unsigned* __restrict__ ticket)
{
  const int tid = threadIdx.x, wv = tid >> 6, lane = tid & 63;
  const int r = lane & 31, h = lane >> 5;
  const int k = blockIdx.x*4 + wv;
  __shared__ float SshA[4][1056];
  __shared__ float blsA[4][1056];
  float* Ssh = SshA[wv];
  float* bls = blsA[wv];
  if (blockIdx.x == 0 && tid == 0) *ticket = 0u;
  const float* cp = chols + (size_t)k*1024 + r*32;
  float4 fa = *(const float4*)(cp + h*8);
  float4 fb = *(const float4*)(cp + h*8 + 4);
  float4 fc = *(const float4*)(cp + 16 + h*8);
  float4 fd = *(const float4*)(cp + 16 + h*8 + 4);
  float v0[8] = {fa.x,fa.y,fa.z,fa.w,fb.x,fb.y,fb.z,fb.w};
  float v1[8] = {fc.x,fc.y,fc.z,fc.w,fd.x,fd.y,fd.z,fd.w};
  short8 hi0, hi1, lo0, lo1;
  #pragma unroll
  for (int j = 0; j < 8; j++) {
    hi0[j] = (short)bfh(v0[j]);  lo0[j] = (short)bfh(v0[j] - bfhf(v0[j]));
    hi1[j] = (short)bfh(v1[j]);  lo1[j] = (short)bfh(v1[j] - bfhf(v1[j]));
  }
  f32x16 acc = {};
  acc = __builtin_amdgcn_mfma_f32_32x32x16_bf16(hi0, hi0, acc, 0,0,0);
  acc = __builtin_amdgcn_mfma_f32_32x32x16_bf16(hi1, hi1, acc, 0,0,0);
  acc = __builtin_amdgcn_mfma_f32_32x32x16_bf16(hi0, lo0, acc, 0,0,0);
  acc = __builtin_amdgcn_mfma_f32_32x32x16_bf16(hi1, lo1, acc, 0,0,0);
  acc = __builtin_amdgcn_mfma_f32_32x32x16_bf16(lo0, hi0, acc, 0,0,0);
  acc = __builtin_amdgcn_mfma_f32_32x32x16_bf16(lo1, hi1, acc, 0,0,0);
  #pragma unroll
  for (int q = 0; q < 16; q++) {
    int row = (q & 3) + 8*(q >> 2) + 4*h;
    Ssh[row*33 + r] = acc[q] + ((row == r) ? 1.0f : 0.0f);
  }
  float a[32];
  #pragma unroll
  for (int j = 0; j < 32; j++) a[j] = Ssh[r*33 + j];
  float ldsum = 0.0f;
  #pragma unroll
  for (int j = 0; j < 32; j++) {
    float dd = __shfl(a[j], j);
    float sq = sqrtf(dd);
    float inv = 1.0f / sq;
    ldsum += __logf(sq);
    float l = a[j] * inv;
    #pragma unroll
    for (int e = j+1; e < 32; e++) {
      float le = __shfl(l, e);
      a[e] = (r >= e) ? fmaf(-l, le, a[e]) : a[e];
    }
    a[j] = (r == j) ? sq : ((r > j) ? l : a[j]);
  }
  #pragma unroll
  for (int j = 0; j < 32; j++) Ssh[r*33 + j] = a[j];
  #pragma unroll 1
  for (int d = 0; d < 32; d++) {          // lane r computes column r of B = L^-1
    float s = (d == r) ? 1.0f : 0.0f;
    for (int j = 0; j < d; j++) s = fmaf(-Ssh[d*33 + j], bls[j*33 + r], s);
    bls[d*33 + r] = s / Ssh[d*33 + d];
  }
  float t0[8], t1[8];
  #pragma unroll
  for (int j = 0; j < 8; j++) {
    t0[j] = bls[r*33 + h*8 + j];
    t1[j] = bls[r*33 + 16 + h*8 + j];
  }
  uint4 s0 = make_uint4(bfh(t0[0])|(bfh(t0[1])<<16), bfh(t0[2])|(bfh(t0[3])<<16),
                        bfh(t0[4])|(bfh(t0[5])<<16), bfh(t0[6])|(bfh(t0[7])<<16));
  uint4 s1 = make_uint4(bfh(t1[0])|(bfh(t1[1])<<16), bfh(t1[2])|(bfh(t1[3])<<16),
                        bfh(t1[4])|(bfh(t1[5])<<16), bfh(t1[6])|(bfh(t1[7])<<16));
  float cvp = 0.0f;
  #pragma unroll
  for (int j = 0; j < 8; j++) {
    cvp = fmaf(t0[j], means[k*32 + h*8 + j], cvp);
    cvp = fmaf(t1[j], means[k*32 + 16 + h*8 + j], cvp);
  }
  float cv = cvp + __shfl_xor(cvp, 32);
  unsigned ch = bfh(cv) ^ 0x8000u;
  unsigned cl = bfh(cv - bfhf(cv)) ^ 0x8000u;
  uint4 s2 = make_uint4((h == 0) ? (ch | (cl<<16)) : 0u, 0u, 0u, 0u);
  Afrag[(k*3 + 0)*64 + lane] = s0;
  Afrag[(k*3 + 1)*64 + lane] = s1;
  Afrag[(k*3 + 2)*64 + lane] = s2;
  if (lane == 0) {
    float wk = wts[k];
    float ld2 = 2.0f*ldsum + DLOG2PIF;
    Kc[k] = LOG2E*(SHIFT - 0.5f*ld2) + log2f(fabsf(wk));
    Sg[k] = (wk < 0.0f) ? -1.0f : 1.0f;
  }
}

// ===== work: 1024 blocks x 256 thr; 1 point-set/wave; pair tail on blk<256 =========
__global__ __launch_bounds__(256) void work_kernel(
    const float* __restrict__ X, const float* __restrict__ means,
    const float* __restrict__ chols, const float* __restrict__ wts,
    const uint4* __restrict__ Afrag, const float* __restrict__ Kc,
    const float* __restrict__ Sg,
    double* __restrict__ pairv, double* __restrict__ partials,
    unsigned* __restrict__ ticket, float* __restrict__ out)
{
  __shared__ __align__(16) char smem[24576];       // fsh (points) / Ssh (pair tail)
  __shared__ float K2sh[32], sksh[32];
  __shared__ double redm[4], reds[4], rtm[4], rts[4], rzm[4], rzs[4];
  __shared__ unsigned lastFlag;
  uint4* fsh = (uint4*)smem;
  const int tid = threadIdx.x, wv = tid >> 6, lane = tid & 63;
  const int r = lane & 31, h = lane >> 5;
  if (tid < 32) { K2sh[tid] = Kc[tid]; sksh[tid] = Sg[tid]; }
  // ---- points: one 32-point MFMA set per wave ----
  const int n0 = (blockIdx.x*4 + wv)*32 + r;
  short8 xh0, xh1, x2c;
  {
    const float* xp = X + (size_t)n0*32;
    float4 fa = *(const float4*)(xp + h*8);
    float4 fb = *(const float4*)(xp + h*8 + 4);
    float4 fc = *(const float4*)(xp + 16 + h*8);
    float4 fd = *(const float4*)(xp + 16 + h*8 + 4);
    float v0[8] = {fa.x,fa.y,fa.z,fa.w,fb.x,fb.y,fb.z,fb.w};
    float v1[8] = {fc.x,fc.y,fc.z,fc.w,fd.x,fd.y,fd.z,fd.w};
    #pragma unroll
    for (int j = 0; j < 8; j++) {
      xh0[j] = (short)bfh(v0[j]);
      xh1[j] = (short)bfh(v1[j]);
      x2c[j] = 0;
    }
    if (h == 0) { x2c[0] = (short)0x3F80; x2c[1] = (short)0x3F80; }   // X2=[1,1,0..]
  }
  float sF = 0.0f;
  #pragma unroll 1
  for (int ph = 0; ph < 4; ph++) {
    __syncthreads();
    const uint4* src = Afrag + ph*1536;
    #pragma unroll
    for (int t = tid; t < 1536; t += 256) fsh[t] = src[t];
    __syncthreads();
    #pragma unroll
    for (int kk = 0; kk < 8; kk++) {
      const short8* fp = (const short8*)(fsh + kk*192);
      short8 a0 = fp[lane], a1 = fp[64+lane], a2 = fp[128+lane];
      const int kidx = ph*8 + kk;
      const float Kk = K2sh[kidx], sk = sksh[kidx];
      f32x16 acc = {};
      acc = __builtin_amdgcn_mfma_f32_32x32x16_bf16(a0, xh0, acc, 0,0,0);
      acc = __builtin_amdgcn_mfma_f32_32x32x16_bf16(a1, xh1, acc, 0,0,0);
      acc = __builtin_amdgcn_mfma_f32_32x32x16_bf16(a2, x2c, acc, 0,0,0);
      float ma = 0.0f, mb = 0.0f;
      #pragma unroll
      for (int q = 0; q < 8; q++) {
        ma = fmaf(acc[q],   acc[q],   ma);
        mb = fmaf(acc[q+8], acc[q+8], mb);
      }
      float m0 = ma + mb;
      m0 += __shfl_xor(m0, 32);
      sF = fmaf(sk, exp2f(fmaf(m0, NEGHALF_LOG2E, Kk)), sF);
    }
  }
  double vm, vs = 1.0;
  if (sF != 0.0f) vm = 2.0*log(fabs((double)sF)) - 2.0*(double)SHIFT;
  else          { vm = -1e300; vs = 0.0; }
  if (lane >= 32) { vm = -1e300; vs = 0.0; }         // upper halves duplicate
  #pragma unroll
  for (int off = 32; off > 0; off >>= 1) {
    double m2 = __shfl_down(vm, off);
    double s2 = __shfl_down(vs, off);
    lse_merge(vm, vs, m2, s2);
  }
  if (lane == 0) { redm[wv] = vm; reds[wv] = vs; }
  __syncthreads();                                   // also protects smem reuse below
  if (tid == 0) {
    for (int w = 1; w < 4; w++) lse_merge(vm, vs, redm[w], reds[w]);
    partials[2*blockIdx.x]   = vm;
    partials[2*blockIdx.x+1] = vs;
  }
  // ---- pair tail: blocks 0..255, wave wv handles pair blockIdx*4+wv ----
  if (blockIdx.x < 256) {
    float* Ssh = (float*)smem + wv*1056;
    const int pid = blockIdx.x*4 + wv, pi = pid >> 5, pj = pid & 31;
    const float* cpi = chols + (size_t)pi*1024 + r*32;
    const float* cpj = chols + (size_t)pj*1024 + r*32;
    float4 ia = *(const float4*)(cpi + h*8);
    float4 ib = *(const float4*)(cpi + h*8 + 4);
    float4 ic = *(const float4*)(cpi + 16 + h*8);
    float4 id = *(const float4*)(cpi + 16 + h*8 + 4);
    float4 ja = *(const float4*)(cpj + h*8);
    float4 jb = *(const float4*)(cpj + h*8 + 4);
    float4 jc = *(const float4*)(cpj + 16 + h*8);
    float4 jd = *(const float4*)(cpj + 16 + h*8 + 4);
    float vi0[8] = {ia.x,ia.y,ia.z,ia.w,ib.x,ib.y,ib.z,ib.w};
    float vi1[8] = {ic.x,ic.y,ic.z,ic.w,id.x,id.y,id.z,id.w};
    float vj0[8] = {ja.x,ja.y,ja.z,ja.w,jb.x,jb.y,jb.z,jb.w};
    float vj1[8] = {jc.x,jc.y,jc.z,jc.w,jd.x,jd.y,jd.z,jd.w};
    short8 I0h,I0l,I1h,I1l,J0h,J0l,J1h,J1l;
    #pragma unroll
    for (int j = 0; j < 8; j++) {
      I0h[j]=(short)bfh(vi0[j]); I0l[j]=(short)bfh(vi0[j]-bfhf(vi0[j]));
      I1h[j]=(short)bfh(vi1[j]); I1l[j]=(short)bfh(vi1[j]-bfhf(vi1[j]));
      J0h[j]=(short)bfh(vj0[j]); J0l[j]=(short)bfh(vj0[j]-bfhf(vj0[j]));
      J1h[j]=(short)bfh(vj1[j]); J1l[j]=(short)bfh(vj1[j]-bfhf(vj1[j]));
    }
    f32x16 pacc = {};
    pacc = __builtin_amdgcn_mfma_f32_32x32x16_bf16(I0h, I0h, pacc, 0,0,0);
    pacc = __builtin_amdgcn_mfma_f32_32x32x16_bf16(I1h, I1h, pacc, 0,0,0);
    pacc = __builtin_amdgcn_mfma_f32_32x32x16_bf16(I0h, I0l, pacc, 0,0,0);
    pacc = __builtin_amdgcn_mfma_f32_32x32x16_bf16(I1h, I1l, pacc, 0,0,0);
    pacc = __builtin_amdgcn_mfma_f32_32x32x16_bf16(I0l, I0h, pacc, 0,0,0);
    pacc = __builtin_amdgcn_mfma_f32_32x32x16_bf16(I1l, I1h, pacc, 0,0,0);
    pacc = __builtin_amdgcn_mfma_f32_32x32x16_bf16(J0h, J0h, pacc, 0,0,0);
    pacc = __builtin_amdgcn_mfma_f32_32x32x16_bf16(J1h, J1h, pacc, 0,0,0);
    pacc = __builtin_amdgcn_mfma_f32_32x32x16_bf16(J0h, J0l, pacc, 0,0,0);
    pacc = __builtin_amdgcn_mfma_f32_32x32x16_bf16(J1h, J1l, pacc, 0,0,0);
    pacc = __builtin_amdgcn_mfma_f32_32x32x16_bf16(J0l, J0h, pacc, 0,0,0);
    pacc = __builtin_amdgcn_mfma_f32_32x32x16_bf16(J1l, J1h, pacc, 0,0,0);
    #pragma unroll
    for (int q = 0; q < 16; q++) {
      int row = (q & 3) + 8*(q >> 2) + 4*h;
      Ssh[row*33 + r] = pacc[q] + ((row == r) ? 2.0f : 0.0f);   // +I from each Sigma
    }
    float a[32];
    #pragma unroll
    for (int j = 0; j < 32; j++) a[j] = Ssh[r*33 + j];
    #pragma unroll
    for (int j = 0; j < 32; j++) {
      float dd = __shfl(a[j], j);
      float sq = sqrtf(dd);
      float inv = 1.0f / sq;
      float l = a[j] * inv;
      #pragma unroll
      for (int e = j+1; e < 32; e++) {
        float le = __shfl(l, e);
        a[e] = (r >= e) ? fmaf(-l, le, a[e]) : a[e];
      }
      a[j] = (r == j) ? sq : ((r > j) ? l : a[j]);
    }
    float acc2 = means[pi*32 + r] - means[pj*32 + r];
    float maha = 0.0f, ldsum = 0.0f;
    #pragma unroll
    for (int d = 0; d < 32; d++) {
      float dd = __shfl(a[d], d);
      float yd = __shfl(acc2, d) / dd;
      maha = fmaf(yd, yd, maha);
      ldsum += __logf(dd);
      acc2 = (r > d) ? fmaf(-a[d], yd, acc2) : acc2;
    }
    if (lane == 0) pairv[pid] = -0.5 * ((double)maha + 2.0*(double)ldsum + DLOG2PI);
  }
  // ---- end-of-kernel ticket + fused final (r6-validated pattern) ----
  __syncthreads();
  if (tid == 0) {
    __threadfence();
    lastFlag = (atomicAdd(ticket, 1u) == NWB - 1) ? 1u : 0u;
  }
  __syncthreads();
  if (lastFlag) {
    __threadfence();
    double tm = -1e300, ts = 0.0;
    for (int p = tid; p < NWB; p += 256) lse_merge(tm, ts, partials[2*p], partials[2*p+1]);
    double zm = -1e300, zs = 0.0;
    for (int p = tid; p < 1024; p += 256) {
      int i = p >> 5, j = p & 31;
      lse_merge(zm, zs, pairv[p], (double)wts[i] * (double)wts[j]);
    }
    #pragma unroll
    for (int off = 32; off > 0; off >>= 1) {
      double a2 = __shfl_down(tm, off), b2 = __shfl_down(ts, off);
      lse_merge(tm, ts, a2, b2);
      double c2 = __shfl_down(zm, off), d2 = __shfl_down(zs, off);
      lse_merge(zm, zs, c2, d2);
    }
    if (lane == 0) { rtm[wv]=tm; rts[wv]=ts; rzm[wv]=zm; rzs[wv]=zs; }
    __syncthreads();
    if (tid == 0) {
      for (int w = 1; w < 4; w++) { lse_merge(tm, ts, rtm[w], rts[w]); lse_merge(zm, zs, rzm[w], rzs[w]); }
      double logT = tm + log(ts);
      double logz = zm + log(zs);
      out[0] = (float)((logz - logT) / (double)NPTS);
    }
  }
}

extern "C" void kernel_launch(void* const* d_in, const int* in_sizes, int n_in,
                              void* d_out, int out_size, void* d_ws, size_t ws_size,
                              hipStream_t stream) {
  const float* X     = (const float*)d_in[0];
  const float* means = (const float*)d_in[1];
  const float* chols = (const float*)d_in[2];
  const float* wts   = (const float*)d_in[3];
  float* out = (float*)d_out;
  char* ws = (char*)d_ws;
  uint4*    Afrag    = (uint4*)ws;                // 98304
  float*    Kc       = (float*)(ws + 98304);      // 128   -> 98432
  float*    Sg       = (float*)(ws + 98432);      // 128   -> 98560
  double*   pairv    = (double*)(ws + 98560);     // 8192  -> 106752
  double*   partials = (double*)(ws + 106752);    // 16384 -> 123136
  unsigned* ticket   = (unsigned*)(ws + 123136);  // 4     -> 123140

  setup_kernel<<<8, 256, 0, stream>>>(means, chols, wts, Afrag, Kc, Sg, ticket);
  work_kernel<<<NWB, 256, 0, stream>>>(X, means, chols, wts, Afrag, Kc, Sg,
                                       pairv, partials, ticket, out);
}

// Round 9
// 152.351 us; speedup vs baseline: 1.4778x; 1.0004x over previous
//
#include <hip/hip_runtime.h>
#include <math.h>

#define NPTS  131072
#define NPTB  512          // point blocks: 256 thr = 4 waves x 2 ptsets x 32 pts
#define NPRB  256          // pair blocks: 4 pairs/block (1 per wave)
#define GRID  (NPTB + NPRB)
#define DLOG2PIF 58.8120661f
#define DLOG2PI  58.81206612467475
#define SHIFT 92.0f
#define NEGHALF_LOG2E -0.72134752044f
#define LOG2E 1.44269504089f

typedef __attribute__((ext_vector_type(8)))  short short8;
typedef __attribute__((ext_vector_type(16))) float f32x16;

static __device__ __forceinline__ unsigned bfh(float f) {    // fp32 -> bf16 bits (RNE)
  unsigned u = __float_as_uint(f);
  return (u + 0x7FFFu + ((u >> 16) & 1u)) >> 16;
}
static __device__ __forceinline__ float bfhf(float f) {
  return __uint_as_float(bfh(f) << 16);
}

// ===== setup: 8 blocks x 256 thr; wave wv handles cluster blockIdx*4+wv ============
// Sigma via 6 split-bf16 MFMAs; register chol; in-register col-parallel L^-1.
__global__ __launch_bounds__(256) void setup_kernel(
    const float* __restrict__ means, const float* __restrict__ chols,
    const float* __restrict__ wts,
    uint4* __restrict__ Afrag, float* __restrict__ Kc, float* __restrict__ Sg,
    unsigned* __restrict__ ticket)
{
  const int tid = threadIdx.x, wv = tid >> 6, lane = tid & 63;
  const int r = lane & 31, h = lane >> 5;
  const int k = blockIdx.x*4 + wv;
  __shared__ float SshA[4][1056];
  __shared__ float blsA[4][1056];
  float* Ssh = SshA[wv];
  float* bls = blsA[wv];
  if (blockIdx.x == 0 && tid == 0) *ticket = 0u;
  const float* cp = chols + (size_t)k*1024 + r*32;
  float4 fa = *(const float4*)(cp + h*8);
  float4 fb = *(const float4*)(cp + h*8 + 4);
  float4 fc = *(const float4*)(cp + 16 + h*8);
  float4 fd = *(const float4*)(cp + 16 + h*8 + 4);
  float v0[8] = {fa.x,fa.y,fa.z,fa.w,fb.x,fb.y,fb.z,fb.w};
  float v1[8] = {fc.x,fc.y,fc.z,fc.w,fd.x,fd.y,fd.z,fd.w};
  short8 hi0, hi1, lo0, lo1;
  #pragma unroll
  for (int j = 0; j < 8; j++) {
    hi0[j] = (short)bfh(v0[j]);  lo0[j] = (short)bfh(v0[j] - bfhf(v0[j]));
    hi1[j] = (short)bfh(v1[j]);  lo1[j] = (short)bfh(v1[j] - bfhf(v1[j]));
  }
  f32x16 acc = {};
  acc = __builtin_amdgcn_mfma_f32_32x32x16_bf16(hi0, hi0, acc, 0,0,0);
  acc = __builtin_amdgcn_mfma_f32_32x32x16_bf16(hi1, hi1, acc, 0,0,0);
  acc = __builtin_amdgcn_mfma_f32_32x32x16_bf16(hi0, lo0, acc, 0,0,0);
  acc = __builtin_amdgcn_mfma_f32_32x32x16_bf16(hi1, lo1, acc, 0,0,0);
  acc = __builtin_amdgcn_mfma_f32_32x32x16_bf16(lo0, hi0, acc, 0,0,0);
  acc = __builtin_amdgcn_mfma_f32_32x32x16_bf16(lo1, hi1, acc, 0,0,0);
  #pragma unroll
  for (int q = 0; q < 16; q++) {
    int row = (q & 3) + 8*(q >> 2) + 4*h;
    Ssh[row*33 + r] = acc[q] + ((row == r) ? 1.0f : 0.0f);
  }
  float a[32];
  #pragma unroll
  for (int j = 0; j < 32; j++) a[j] = Ssh[r*33 + j];   // lane r holds row r
  float ldsum = 0.0f;
  #pragma unroll
  for (int j = 0; j < 32; j++) {
    float dd = __shfl(a[j], j);
    float sq = sqrtf(dd);
    float inv = 1.0f / sq;
    ldsum += __logf(sq);
    float l = a[j] * inv;
    #pragma unroll
    for (int e = j+1; e < 32; e++) {
      float le = __shfl(l, e);
      a[e] = (r >= e) ? fmaf(-l, le, a[e]) : a[e];
    }
    a[j] = (r == j) ? sq : ((r > j) ? l : a[j]);
  }
  // in-register column-parallel inversion: lane r computes column r of B = L^-1
  float bcol[32];
  #pragma unroll
  for (int d = 0; d < 32; d++) {
    float s = (d == r) ? 1.0f : 0.0f;
    #pragma unroll
    for (int j = 0; j < d; j++) s = fmaf(-__shfl(a[j], d), bcol[j], s);
    bcol[d] = s / __shfl(a[d], d);
  }
  // transpose cols -> rows via per-wave LDS slab (same-wave LDS ordering)
  if (lane < 32) {
    #pragma unroll
    for (int d = 0; d < 32; d++) bls[d*33 + r] = bcol[d];
  }
  float t0[8], t1[8];
  #pragma unroll
  for (int j = 0; j < 8; j++) {
    t0[j] = bls[r*33 + h*8 + j];
    t1[j] = bls[r*33 + 16 + h*8 + j];
  }
  uint4 s0 = make_uint4(bfh(t0[0])|(bfh(t0[1])<<16), bfh(t0[2])|(bfh(t0[3])<<16),
                        bfh(t0[4])|(bfh(t0[5])<<16), bfh(t0[6])|(bfh(t0[7])<<16));
  uint4 s1 = make_uint4(bfh(t1[0])|(bfh(t1[1])<<16), bfh(t1[2])|(bfh(t1[3])<<16),
                        bfh(t1[4])|(bfh(t1[5])<<16), bfh(t1[6])|(bfh(t1[7])<<16));
  float cvp = 0.0f;
  #pragma unroll
  for (int j = 0; j < 8; j++) {
    cvp = fmaf(t0[j], means[k*32 + h*8 + j], cvp);
    cvp = fmaf(t1[j], means[k*32 + 16 + h*8 + j], cvp);
  }
  float cv = cvp + __shfl_xor(cvp, 32);
  unsigned ch = bfh(cv) ^ 0x8000u;
  unsigned cl = bfh(cv - bfhf(cv)) ^ 0x8000u;
  uint4 s2 = make_uint4((h == 0) ? (ch | (cl<<16)) : 0u, 0u, 0u, 0u);
  Afrag[(k*3 + 0)*64 + lane] = s0;
  Afrag[(k*3 + 1)*64 + lane] = s1;
  Afrag[(k*3 + 2)*64 + lane] = s2;
  if (lane == 0) {
    float wk = wts[k];
    float ld2 = 2.0f*ldsum + DLOG2PIF;
    Kc[k] = LOG2E*(SHIFT - 0.5f*ld2) + log2f(fabsf(wk));
    Sg[k] = (wk < 0.0f) ? -1.0f : 1.0f;
  }
}

// ===== work: 512 point blocks + 256 pair blocks; fused last-block final ============
__global__ __launch_bounds__(256) void work_kernel(
    const float* __restrict__ X, const float* __restrict__ means,
    const float* __restrict__ chols, const float* __restrict__ wts,
    const uint4* __restrict__ Afrag, const float* __restrict__ Kc,
    const float* __restrict__ Sg,
    double* __restrict__ zterm, double* __restrict__ partials,
    unsigned* __restrict__ ticket, float* __restrict__ out)
{
  __shared__ __align__(16) char smem[49152];     // fsh (points) / Ssh (pairs)
  __shared__ float K2sh[32], sksh[32];
  __shared__ double redd[4], redz[4];
  __shared__ unsigned lastFlag;
  const int tid = threadIdx.x, wv = tid >> 6, lane = tid & 63;
  const int r = lane & 31, h = lane >> 5;
  if (blockIdx.x < NPTB) {
    // ================= points: 4 waves x 2 ptsets x 32 pts =================
    uint4* fsh = (uint4*)smem;
    if (tid < 32) { K2sh[tid] = Kc[tid]; sksh[tid] = Sg[tid]; }
    const int n0 = blockIdx.x*256 + wv*64 + r;   // set0; set1 = n0+32
    short8 xh00, xh01, xh10, xh11, x2c;
    {
      const float* xp0 = X + (size_t)n0*32;
      const float* xp1 = X + (size_t)(n0+32)*32;
      float4 fa = *(const float4*)(xp0 + h*8);
      float4 fb = *(const float4*)(xp0 + h*8 + 4);
      float4 fc = *(const float4*)(xp0 + 16 + h*8);
      float4 fd = *(const float4*)(xp0 + 16 + h*8 + 4);
      float4 ga = *(const float4*)(xp1 + h*8);
      float4 gb = *(const float4*)(xp1 + h*8 + 4);
      float4 gc = *(const float4*)(xp1 + 16 + h*8);
      float4 gd = *(const float4*)(xp1 + 16 + h*8 + 4);
      float v00[8] = {fa.x,fa.y,fa.z,fa.w,fb.x,fb.y,fb.z,fb.w};
      float v01[8] = {fc.x,fc.y,fc.z,fc.w,fd.x,fd.y,fd.z,fd.w};
      float v10[8] = {ga.x,ga.y,ga.z,ga.w,gb.x,gb.y,gb.z,gb.w};
      float v11[8] = {gc.x,gc.y,gc.z,gc.w,gd.x,gd.y,gd.z,gd.w};
      #pragma unroll
      for (int j = 0; j < 8; j++) {
        xh00[j] = (short)bfh(v00[j]);  xh01[j] = (short)bfh(v01[j]);
        xh10[j] = (short)bfh(v10[j]);  xh11[j] = (short)bfh(v11[j]);
        x2c[j] = 0;
      }
      if (h == 0) { x2c[0] = (short)0x3F80; x2c[1] = (short)0x3F80; }
    }
    float sF0 = 0.0f, sF1 = 0.0f;
    #pragma unroll 1
    for (int ph = 0; ph < 2; ph++) {
      __syncthreads();
      const uint4* src = Afrag + ph*3072;
      #pragma unroll
      for (int t = tid; t < 3072; t += 256) fsh[t] = src[t];
      __syncthreads();
      #pragma unroll 4
      for (int kk = 0; kk < 16; kk++) {
        const short8* fp = (const short8*)(fsh + kk*192);
        short8 a0 = fp[lane], a1 = fp[64+lane], a2 = fp[128+lane];
        const int kidx = ph*16 + kk;
        const float Kk = K2sh[kidx], sk = sksh[kidx];
        f32x16 acc0 = {}, acc1 = {};
        acc0 = __builtin_amdgcn_mfma_f32_32x32x16_bf16(a0, xh00, acc0, 0,0,0);
        acc0 = __builtin_amdgcn_mfma_f32_32x32x16_bf16(a1, xh01, acc0, 0,0,0);
        acc0 = __builtin_amdgcn_mfma_f32_32x32x16_bf16(a2, x2c,  acc0, 0,0,0);
        acc1 = __builtin_amdgcn_mfma_f32_32x32x16_bf16(a0, xh10, acc1, 0,0,0);
        acc1 = __builtin_amdgcn_mfma_f32_32x32x16_bf16(a1, xh11, acc1, 0,0,0);
        acc1 = __builtin_amdgcn_mfma_f32_32x32x16_bf16(a2, x2c,  acc1, 0,0,0);
        float m0a=0.f, m0b=0.f, m1a=0.f, m1b=0.f;
        #pragma unroll
        for (int q = 0; q < 8; q++) {
          m0a = fmaf(acc0[q],   acc0[q],   m0a);
          m0b = fmaf(acc0[q+8], acc0[q+8], m0b);
          m1a = fmaf(acc1[q],   acc1[q],   m1a);
          m1b = fmaf(acc1[q+8], acc1[q+8], m1b);
        }
        float m0 = m0a + m0b, m1 = m1a + m1b;
        m0 += __shfl_xor(m0, 32);
        m1 += __shfl_xor(m1, 32);
        sF0 = fmaf(sk, exp2f(fmaf(m0, NEGHALF_LOG2E, Kk)), sF0);
        sF1 = fmaf(sk, exp2f(fmaf(m1, NEGHALF_LOG2E, Kk)), sF1);
      }
    }
    // T-partial: plain fp64 sum of sF^2 (log-shift folded: T = sum * e^{-184})
    double Tp = (double)sF0*(double)sF0 + (double)sF1*(double)sF1;
    if (lane >= 32) Tp = 0.0;                    // upper halves duplicate
    #pragma unroll
    for (int off = 32; off > 0; off >>= 1) Tp += __shfl_down(Tp, off);
    if (lane == 0) redd[wv] = Tp;
    __syncthreads();
    if (tid == 0) partials[blockIdx.x] = redd[0] + redd[1] + redd[2] + redd[3];
  } else {
    // ================= pairs: 1 pair per wave, from chols ==================
    float* Ssh = (float*)smem + wv*1056;
    const int pid = (blockIdx.x - NPTB)*4 + wv, pi = pid >> 5, pj = pid & 31;
    const float* cpi = chols + (size_t)pi*1024 + r*32;
    const float* cpj = chols + (size_t)pj*1024 + r*32;
    float4 ia = *(const float4*)(cpi + h*8);
    float4 ib = *(const float4*)(cpi + h*8 + 4);
    float4 ic = *(const float4*)(cpi + 16 + h*8);
    float4 id = *(const float4*)(cpi + 16 + h*8 + 4);
    float4 ja = *(const float4*)(cpj + h*8);
    float4 jb = *(const float4*)(cpj + h*8 + 4);
    float4 jc = *(const float4*)(cpj + 16 + h*8);
    float4 jd = *(const float4*)(cpj + 16 + h*8 + 4);
    float vi0[8] = {ia.x,ia.y,ia.z,ia.w,ib.x,ib.y,ib.z,ib.w};
    float vi1[8] = {ic.x,ic.y,ic.z,ic.w,id.x,id.y,id.z,id.w};
    float vj0[8] = {ja.x,ja.y,ja.z,ja.w,jb.x,jb.y,jb.z,jb.w};
    float vj1[8] = {jc.x,jc.y,jc.z,jc.w,jd.x,jd.y,jd.z,jd.w};
    short8 I0h,I0l,I1h,I1l,J0h,J0l,J1h,J1l;
    #pragma unroll
    for (int j = 0; j < 8; j++) {
      I0h[j]=(short)bfh(vi0[j]); I0l[j]=(short)bfh(vi0[j]-bfhf(vi0[j]));
      I1h[j]=(short)bfh(vi1[j]); I1l[j]=(short)bfh(vi1[j]-bfhf(vi1[j]));
      J0h[j]=(short)bfh(vj0[j]); J0l[j]=(short)bfh(vj0[j]-bfhf(vj0[j]));
      J1h[j]=(short)bfh(vj1[j]); J1l[j]=(short)bfh(vj1[j]-bfhf(vj1[j]));
    }
    f32x16 pacc = {};
    pacc = __builtin_amdgcn_mfma_f32_32x32x16_bf16(I0h, I0h, pacc, 0,0,0);
    pacc = __builtin_amdgcn_mfma_f32_32x32x16_bf16(I1h, I1h, pacc, 0,0,0);
    pacc = __builtin_amdgcn_mfma_f32_32x32x16_bf16(I0h, I0l, pacc, 0,0,0);
    pacc = __builtin_amdgcn_mfma_f32_32x32x16_bf16(I1h, I1l, pacc, 0,0,0);
    pacc = __builtin_amdgcn_mfma_f32_32x32x16_bf16(I0l, I0h, pacc, 0,0,0);
    pacc = __builtin_amdgcn_mfma_f32_32x32x16_bf16(I1l, I1h, pacc, 0,0,0);
    pacc = __builtin_amdgcn_mfma_f32_32x32x16_bf16(J0h, J0h, pacc, 0,0,0);
    pacc = __builtin_amdgcn_mfma_f32_32x32x16_bf16(J1h, J1h, pacc, 0,0,0);
    pacc = __builtin_amdgcn_mfma_f32_32x32x16_bf16(J0h, J0l, pacc, 0,0,0);
    pacc = __builtin_amdgcn_mfma_f32_32x32x16_bf16(J1h, J1l, pacc, 0,0,0);
    pacc = __builtin_amdgcn_mfma_f32_32x32x16_bf16(J0l, J0h, pacc, 0,0,0);
    pacc = __builtin_amdgcn_mfma_f32_32x32x16_bf16(J1l, J1h, pacc, 0,0,0);
    #pragma unroll
    for (int q = 0; q < 16; q++) {
      int row = (q & 3) + 8*(q >> 2) + 4*h;
      Ssh[row*33 + r] = pacc[q] + ((row == r) ? 2.0f : 0.0f);
    }
    float a[32];
    #pragma unroll
    for (int j = 0; j < 32; j++) a[j] = Ssh[r*33 + j];
    #pragma unroll
    for (int j = 0; j < 32; j++) {
      float dd = __shfl(a[j], j);
      float sq = sqrtf(dd);
      float inv = 1.0f / sq;
      float l = a[j] * inv;
      #pragma unroll
      for (int e = j+1; e < 32; e++) {
        float le = __shfl(l, e);
        a[e] = (r >= e) ? fmaf(-l, le, a[e]) : a[e];
      }
      a[j] = (r == j) ? sq : ((r > j) ? l : a[j]);
    }
    float acc2 = means[pi*32 + r] - means[pj*32 + r];
    float maha = 0.0f, ldsum = 0.0f;
    #pragma unroll
    for (int d = 0; d < 32; d++) {
      float dd = __shfl(a[d], d);
      float yd = __shfl(acc2, d) / dd;
      maha = fmaf(yd, yd, maha);
      ldsum += __logf(dd);
      acc2 = (r > d) ? fmaf(-a[d], yd, acc2) : acc2;
    }
    if (lane == 0) {
      double vd = -0.5 * ((double)maha + 2.0*(double)ldsum + DLOG2PI);
      zterm[pid] = (double)wts[pi] * (double)wts[pj] * exp(vd);
    }
  }
  // ================= end-of-kernel ticket + fused final ====================
  __syncthreads();
  if (tid == 0) {
    __threadfence();
    lastFlag = (atomicAdd(ticket, 1u) == GRID - 1) ? 1u : 0u;
  }
  __syncthreads();
  if (lastFlag) {
    __threadfence();
    double t = 0.0, z = 0.0;
    for (int p = tid; p < NPTB; p += 256) t += partials[p];
    for (int p = tid; p < 1024; p += 256) z += zterm[p];
    #pragma unroll
    for (int off = 32; off > 0; off >>= 1) {
      t += __shfl_down(t, off);
      z += __shfl_down(z, off);
    }
    if (lane == 0) { redd[wv] = t; redz[wv] = z; }
    __syncthreads();
    if (tid == 0) {
      t = redd[0] + redd[1] + redd[2] + redd[3];
      z = redz[0] + redz[1] + redz[2] + redz[3];
      double logT = log(t) - 2.0*(double)SHIFT;
      double logz = log(z);
      out[0] = (float)((logz - logT) / (double)NPTS);
    }
  }
}

extern "C" void kernel_launch(void* const* d_in, const int* in_sizes, int n_in,
                              void* d_out, int out_size, void* d_ws, size_t ws_size,
                              hipStream_t stream) {
  const float* X     = (const float*)d_in[0];
  const float* means = (const float*)d_in[1];
  const float* chols = (const float*)d_in[2];
  const float* wts   = (const float*)d_in[3];
  float* out = (float*)d_out;
  char* ws = (char*)d_ws;
  uint4*    Afrag    = (uint4*)ws;                // 98304
  float*    Kc       = (float*)(ws + 98304);      // 128   -> 98432
  float*    Sg       = (float*)(ws + 98432);      // 128   -> 98560
  double*   zterm    = (double*)(ws + 98560);     // 8192  -> 106752
  double*   partials = (double*)(ws + 106752);    // 4096  -> 110848
  unsigned* ticket   = (unsigned*)(ws + 110848);  // 4     -> 110852

  setup_kernel<<<8, 256, 0, stream>>>(means, chols, wts, Afrag, Kc, Sg, ticket);
  work_kernel<<<GRID, 256, 0, stream>>>(X, means, chols, wts, Afrag, Kc, Sg,
                                        zterm, partials, ticket, out);
}

// Round 10
// 132.891 us; speedup vs baseline: 1.6942x; 1.1464x over previous
//
#include <hip/hip_runtime.h>
#include <math.h>

#define NPTS  131072
#define NPTB  512          // point blocks: 256 thr = 4 waves x 2 ptsets x 32 pts
#define NPRB  256          // pair blocks: 4 pairs/block (1 per wave)
#define GRID  (NPTB + NPRB)
#define DLOG2PIF 58.8120661f
#define DLOG2PI  58.81206612467475
#define SHIFT 92.0f
#define NEGHALF_LOG2E -0.72134752044f
#define LOG2E 1.44269504089f

typedef __attribute__((ext_vector_type(8)))  short short8;
typedef __attribute__((ext_vector_type(16))) float f32x16;

static __device__ __forceinline__ unsigned bfh(float f) {    // fp32 -> bf16 bits (RNE)
  unsigned u = __float_as_uint(f);
  return (u + 0x7FFFu + ((u >> 16) & 1u)) >> 16;
}
static __device__ __forceinline__ float bfhf(float f) {
  return __uint_as_float(bfh(f) << 16);
}

// ===== setup: 8 blocks x 256 thr; wave wv handles cluster blockIdx*4+wv ============
// Sigma via 6 split-bf16 MFMAs; register chol; r6-validated LDS-rolled inversion
// (VGPR ~72, no spills — in-register unrolled inversion spills at 256 VGPR, r9).
__global__ __launch_bounds__(256) void setup_kernel(
    const float* __restrict__ means, const float* __restrict__ chols,
    const float* __restrict__ wts,
    uint4* __restrict__ Afrag, float* __restrict__ Kc, float* __restrict__ Sg,
    unsigned* __restrict__ ticket)
{
  const int tid = threadIdx.x, wv = tid >> 6, lane = tid & 63;
  const int r = lane & 31, h = lane >> 5;
  const int k = blockIdx.x*4 + wv;
  __shared__ float SshA[4][1056];
  __shared__ float blsA[4][1056];
  float* Ssh = SshA[wv];
  float* bls = blsA[wv];
  if (blockIdx.x == 0 && tid == 0) *ticket = 0u;
  const float* cp = chols + (size_t)k*1024 + r*32;
  float4 fa = *(const float4*)(cp + h*8);
  float4 fb = *(const float4*)(cp + h*8 + 4);
  float4 fc = *(const float4*)(cp + 16 + h*8);
  float4 fd = *(const float4*)(cp + 16 + h*8 + 4);
  float v0[8] = {fa.x,fa.y,fa.z,fa.w,fb.x,fb.y,fb.z,fb.w};
  float v1[8] = {fc.x,fc.y,fc.z,fc.w,fd.x,fd.y,fd.z,fd.w};
  short8 hi0, hi1, lo0, lo1;
  #pragma unroll
  for (int j = 0; j < 8; j++) {
    hi0[j] = (short)bfh(v0[j]);  lo0[j] = (short)bfh(v0[j] - bfhf(v0[j]));
    hi1[j] = (short)bfh(v1[j]);  lo1[j] = (short)bfh(v1[j] - bfhf(v1[j]));
  }
  f32x16 acc = {};
  acc = __builtin_amdgcn_mfma_f32_32x32x16_bf16(hi0, hi0, acc, 0,0,0);
  acc = __builtin_amdgcn_mfma_f32_32x32x16_bf16(hi1, hi1, acc, 0,0,0);
  acc = __builtin_amdgcn_mfma_f32_32x32x16_bf16(hi0, lo0, acc, 0,0,0);
  acc = __builtin_amdgcn_mfma_f32_32x32x16_bf16(hi1, lo1, acc, 0,0,0);
  acc = __builtin_amdgcn_mfma_f32_32x32x16_bf16(lo0, hi0, acc, 0,0,0);
  acc = __builtin_amdgcn_mfma_f32_32x32x16_bf16(lo1, hi1, acc, 0,0,0);
  #pragma unroll
  for (int q = 0; q < 16; q++) {
    int row = (q & 3) + 8*(q >> 2) + 4*h;
    Ssh[row*33 + r] = acc[q] + ((row == r) ? 1.0f : 0.0f);
  }
  float a[32];
  #pragma unroll
  for (int j = 0; j < 32; j++) a[j] = Ssh[r*33 + j];   // lane r holds row r
  float ldsum = 0.0f;
  #pragma unroll
  for (int j = 0; j < 32; j++) {
    float dd = __shfl(a[j], j);
    float sq = sqrtf(dd);
    float inv = 1.0f / sq;
    ldsum += __logf(sq);
    float l = a[j] * inv;
    #pragma unroll
    for (int e = j+1; e < 32; e++) {
      float le = __shfl(l, e);
      a[e] = (r >= e) ? fmaf(-l, le, a[e]) : a[e];
    }
    a[j] = (r == j) ? sq : ((r > j) ? l : a[j]);
  }
  // L rows -> LDS (a[] dead afterwards; keeps register pressure low)
  #pragma unroll
  for (int j = 0; j < 32; j++) Ssh[r*33 + j] = a[j];
  // rolled column-parallel inversion: lane r computes column r of B = L^-1
  // (broadcast reads of Ssh; per-lane reads/writes of bls column r)
  #pragma unroll 1
  for (int d = 0; d < 32; d++) {
    float s = (d == r) ? 1.0f : 0.0f;
    for (int j = 0; j < d; j++) s = fmaf(-Ssh[d*33 + j], bls[j*33 + r], s);
    bls[d*33 + r] = s / Ssh[d*33 + d];
  }
  float t0[8], t1[8];
  #pragma unroll
  for (int j = 0; j < 8; j++) {
    t0[j] = bls[r*33 + h*8 + j];
    t1[j] = bls[r*33 + 16 + h*8 + j];
  }
  uint4 s0 = make_uint4(bfh(t0[0])|(bfh(t0[1])<<16), bfh(t0[2])|(bfh(t0[3])<<16),
                        bfh(t0[4])|(bfh(t0[5])<<16), bfh(t0[6])|(bfh(t0[7])<<16));
  uint4 s1 = make_uint4(bfh(t1[0])|(bfh(t1[1])<<16), bfh(t1[2])|(bfh(t1[3])<<16),
                        bfh(t1[4])|(bfh(t1[5])<<16), bfh(t1[6])|(bfh(t1[7])<<16));
  float cvp = 0.0f;
  #pragma unroll
  for (int j = 0; j < 8; j++) {
    cvp = fmaf(t0[j], means[k*32 + h*8 + j], cvp);
    cvp = fmaf(t1[j], means[k*32 + 16 + h*8 + j], cvp);
  }
  float cv = cvp + __shfl_xor(cvp, 32);
  unsigned ch = bfh(cv) ^ 0x8000u;
  unsigned cl = bfh(cv - bfhf(cv)) ^ 0x8000u;
  uint4 s2 = make_uint4((h == 0) ? (ch | (cl<<16)) : 0u, 0u, 0u, 0u);
  Afrag[(k*3 + 0)*64 + lane] = s0;
  Afrag[(k*3 + 1)*64 + lane] = s1;
  Afrag[(k*3 + 2)*64 + lane] = s2;
  if (lane == 0) {
    float wk = wts[k];
    float ld2 = 2.0f*ldsum + DLOG2PIF;
    Kc[k] = LOG2E*(SHIFT - 0.5f*ld2) + log2f(fabsf(wk));
    Sg[k] = (wk < 0.0f) ? -1.0f : 1.0f;
  }
}

// ===== work: 512 point blocks + 256 pair blocks; fused last-block final ============
__global__ __launch_bounds__(256) void work_kernel(
    const float* __restrict__ X, const float* __restrict__ means,
    const float* __restrict__ chols, const float* __restrict__ wts,
    const uint4* __restrict__ Afrag, const float* __restrict__ Kc,
    const float* __restrict__ Sg,
    double* __restrict__ zterm, double* __restrict__ partials,
    unsigned* __restrict__ ticket, float* __restrict__ out)
{
  __shared__ __align__(16) char smem[49152];     // fsh (points) / Ssh (pairs)
  __shared__ float K2sh[32], sksh[32];
  __shared__ double redd[4], redz[4];
  __shared__ unsigned lastFlag;
  const int tid = threadIdx.x, wv = tid >> 6, lane = tid & 63;
  const int r = lane & 31, h = lane >> 5;
  if (blockIdx.x < NPTB) {
    // ================= points: 4 waves x 2 ptsets x 32 pts =================
    uint4* fsh = (uint4*)smem;
    if (tid < 32) { K2sh[tid] = Kc[tid]; sksh[tid] = Sg[tid]; }
    const int n0 = blockIdx.x*256 + wv*64 + r;   // set0; set1 = n0+32
    short8 xh00, xh01, xh10, xh11, x2c;
    {
      const float* xp0 = X + (size_t)n0*32;
      const float* xp1 = X + (size_t)(n0+32)*32;
      float4 fa = *(const float4*)(xp0 + h*8);
      float4 fb = *(const float4*)(xp0 + h*8 + 4);
      float4 fc = *(const float4*)(xp0 + 16 + h*8);
      float4 fd = *(const float4*)(xp0 + 16 + h*8 + 4);
      float4 ga = *(const float4*)(xp1 + h*8);
      float4 gb = *(const float4*)(xp1 + h*8 + 4);
      float4 gc = *(const float4*)(xp1 + 16 + h*8);
      float4 gd = *(const float4*)(xp1 + 16 + h*8 + 4);
      float v00[8] = {fa.x,fa.y,fa.z,fa.w,fb.x,fb.y,fb.z,fb.w};
      float v01[8] = {fc.x,fc.y,fc.z,fc.w,fd.x,fd.y,fd.z,fd.w};
      float v10[8] = {ga.x,ga.y,ga.z,ga.w,gb.x,gb.y,gb.z,gb.w};
      float v11[8] = {gc.x,gc.y,gc.z,gc.w,gd.x,gd.y,gd.z,gd.w};
      #pragma unroll
      for (int j = 0; j < 8; j++) {
        xh00[j] = (short)bfh(v00[j]);  xh01[j] = (short)bfh(v01[j]);
        xh10[j] = (short)bfh(v10[j]);  xh11[j] = (short)bfh(v11[j]);
        x2c[j] = 0;
      }
      if (h == 0) { x2c[0] = (short)0x3F80; x2c[1] = (short)0x3F80; }
    }
    float sF0 = 0.0f, sF1 = 0.0f;
    #pragma unroll 1
    for (int ph = 0; ph < 2; ph++) {
      __syncthreads();
      const uint4* src = Afrag + ph*3072;
      #pragma unroll
      for (int t = tid; t < 3072; t += 256) fsh[t] = src[t];
      __syncthreads();
      #pragma unroll 4
      for (int kk = 0; kk < 16; kk++) {
        const short8* fp = (const short8*)(fsh + kk*192);
        short8 a0 = fp[lane], a1 = fp[64+lane], a2 = fp[128+lane];
        const int kidx = ph*16 + kk;
        const float Kk = K2sh[kidx], sk = sksh[kidx];
        f32x16 acc0 = {}, acc1 = {};
        acc0 = __builtin_amdgcn_mfma_f32_32x32x16_bf16(a0, xh00, acc0, 0,0,0);
        acc0 = __builtin_amdgcn_mfma_f32_32x32x16_bf16(a1, xh01, acc0, 0,0,0);
        acc0 = __builtin_amdgcn_mfma_f32_32x32x16_bf16(a2, x2c,  acc0, 0,0,0);
        acc1 = __builtin_amdgcn_mfma_f32_32x32x16_bf16(a0, xh10, acc1, 0,0,0);
        acc1 = __builtin_amdgcn_mfma_f32_32x32x16_bf16(a1, xh11, acc1, 0,0,0);
        acc1 = __builtin_amdgcn_mfma_f32_32x32x16_bf16(a2, x2c,  acc1, 0,0,0);
        float m0a=0.f, m0b=0.f, m1a=0.f, m1b=0.f;
        #pragma unroll
        for (int q = 0; q < 8; q++) {
          m0a = fmaf(acc0[q],   acc0[q],   m0a);
          m0b = fmaf(acc0[q+8], acc0[q+8], m0b);
          m1a = fmaf(acc1[q],   acc1[q],   m1a);
          m1b = fmaf(acc1[q+8], acc1[q+8], m1b);
        }
        float m0 = m0a + m0b, m1 = m1a + m1b;
        m0 += __shfl_xor(m0, 32);
        m1 += __shfl_xor(m1, 32);
        sF0 = fmaf(sk, exp2f(fmaf(m0, NEGHALF_LOG2E, Kk)), sF0);
        sF1 = fmaf(sk, exp2f(fmaf(m1, NEGHALF_LOG2E, Kk)), sF1);
      }
    }
    // T-partial: plain fp64 sum of sF^2 (log-shift folded: T = sum * e^{-184})
    double Tp = (double)sF0*(double)sF0 + (double)sF1*(double)sF1;
    if (lane >= 32) Tp = 0.0;                    // upper halves duplicate
    #pragma unroll
    for (int off = 32; off > 0; off >>= 1) Tp += __shfl_down(Tp, off);
    if (lane == 0) redd[wv] = Tp;
    __syncthreads();
    if (tid == 0) partials[blockIdx.x] = redd[0] + redd[1] + redd[2] + redd[3];
  } else {
    // ================= pairs: 1 pair per wave, from chols ==================
    float* Ssh = (float*)smem + wv*1056;
    const int pid = (blockIdx.x - NPTB)*4 + wv, pi = pid >> 5, pj = pid & 31;
    const float* cpi = chols + (size_t)pi*1024 + r*32;
    const float* cpj = chols + (size_t)pj*1024 + r*32;
    float4 ia = *(const float4*)(cpi + h*8);
    float4 ib = *(const float4*)(cpi + h*8 + 4);
    float4 ic = *(const float4*)(cpi + 16 + h*8);
    float4 id = *(const float4*)(cpi + 16 + h*8 + 4);
    float4 ja = *(const float4*)(cpj + h*8);
    float4 jb = *(const float4*)(cpj + h*8 + 4);
    float4 jc = *(const float4*)(cpj + 16 + h*8);
    float4 jd = *(const float4*)(cpj + 16 + h*8 + 4);
    float vi0[8] = {ia.x,ia.y,ia.z,ia.w,ib.x,ib.y,ib.z,ib.w};
    float vi1[8] = {ic.x,ic.y,ic.z,ic.w,id.x,id.y,id.z,id.w};
    float vj0[8] = {ja.x,ja.y,ja.z,ja.w,jb.x,jb.y,jb.z,jb.w};
    float vj1[8] = {jc.x,jc.y,jc.z,jc.w,jd.x,jd.y,jd.z,jd.w};
    short8 I0h,I0l,I1h,I1l,J0h,J0l,J1h,J1l;
    #pragma unroll
    for (int j = 0; j < 8; j++) {
      I0h[j]=(short)bfh(vi0[j]); I0l[j]=(short)bfh(vi0[j]-bfhf(vi0[j]));
      I1h[j]=(short)bfh(vi1[j]); I1l[j]=(short)bfh(vi1[j]-bfhf(vi1[j]));
      J0h[j]=(short)bfh(vj0[j]); J0l[j]=(short)bfh(vj0[j]-bfhf(vj0[j]));
      J1h[j]=(short)bfh(vj1[j]); J1l[j]=(short)bfh(vj1[j]-bfhf(vj1[j]));
    }
    f32x16 pacc = {};
    pacc = __builtin_amdgcn_mfma_f32_32x32x16_bf16(I0h, I0h, pacc, 0,0,0);
    pacc = __builtin_amdgcn_mfma_f32_32x32x16_bf16(I1h, I1h, pacc, 0,0,0);
    pacc = __builtin_amdgcn_mfma_f32_32x32x16_bf16(I0h, I0l, pacc, 0,0,0);
    pacc = __builtin_amdgcn_mfma_f32_32x32x16_bf16(I1h, I1l, pacc, 0,0,0);
    pacc = __builtin_amdgcn_mfma_f32_32x32x16_bf16(I0l, I0h, pacc, 0,0,0);
    pacc = __builtin_amdgcn_mfma_f32_32x32x16_bf16(I1l, I1h, pacc, 0,0,0);
    pacc = __builtin_amdgcn_mfma_f32_32x32x16_bf16(J0h, J0h, pacc, 0,0,0);
    pacc = __builtin_amdgcn_mfma_f32_32x32x16_bf16(J1h, J1h, pacc, 0,0,0);
    pacc = __builtin_amdgcn_mfma_f32_32x32x16_bf16(J0h, J0l, pacc, 0,0,0);
    pacc = __builtin_amdgcn_mfma_f32_32x32x16_bf16(J1h, J1l, pacc, 0,0,0);
    pacc = __builtin_amdgcn_mfma_f32_32x32x16_bf16(J0l, J0h, pacc, 0,0,0);
    pacc = __builtin_amdgcn_mfma_f32_32x32x16_bf16(J1l, J1h, pacc, 0,0,0);
    #pragma unroll
    for (int q = 0; q < 16; q++) {
      int row = (q & 3) + 8*(q >> 2) + 4*h;
      Ssh[row*33 + r] = pacc[q] + ((row == r) ? 2.0f : 0.0f);
    }
    float a[32];
    #pragma unroll
    for (int j = 0; j < 32; j++) a[j] = Ssh[r*33 + j];
    #pragma unroll
    for (int j = 0; j < 32; j++) {
      float dd = __shfl(a[j], j);
      float sq = sqrtf(dd);
      float inv = 1.0f / sq;
      float l = a[j] * inv;
      #pragma unroll
      for (int e = j+1; e < 32; e++) {
        float le = __shfl(l, e);
        a[e] = (r >= e) ? fmaf(-l, le, a[e]) : a[e];
      }
      a[j] = (r == j) ? sq : ((r > j) ? l : a[j]);
    }
    float acc2 = means[pi*32 + r] - means[pj*32 + r];
    float maha = 0.0f, ldsum = 0.0f;
    #pragma unroll
    for (int d = 0; d < 32; d++) {
      float dd = __shfl(a[d], d);
      float yd = __shfl(acc2, d) / dd;
      maha = fmaf(yd, yd, maha);
      ldsum += __logf(dd);
      acc2 = (r > d) ? fmaf(-a[d], yd, acc2) : acc2;
    }
    if (lane == 0) {
      double vd = -0.5 * ((double)maha + 2.0*(double)ldsum + DLOG2PI);
      zterm[pid] = (double)wts[pi] * (double)wts[pj] * exp(vd);
    }
  }
  // ================= end-of-kernel ticket + fused final ====================
  __syncthreads();
  if (tid == 0) {
    __threadfence();
    lastFlag = (atomicAdd(ticket, 1u) == GRID - 1) ? 1u : 0u;
  }
  __syncthreads();
  if (lastFlag) {
    __threadfence();
    double t = 0.0, z = 0.0;
    for (int p = tid; p < NPTB; p += 256) t += partials[p];
    for (int p = tid; p < 1024; p += 256) z += zterm[p];
    #pragma unroll
    for (int off = 32; off > 0; off >>= 1) {
      t += __shfl_down(t, off);
      z += __shfl_down(z, off);
    }
    if (lane == 0) { redd[wv] = t; redz[wv] = z; }
    __syncthreads();
    if (tid == 0) {
      t = redd[0] + redd[1] + redd[2] + redd[3];
      z = redz[0] + redz[1] + redz[2] + redz[3];
      double logT = log(t) - 2.0*(double)SHIFT;
      double logz = log(z);
      out[0] = (float)((logz - logT) / (double)NPTS);
    }
  }
}

extern "C" void kernel_launch(void* const* d_in, const int* in_sizes, int n_in,
                              void* d_out, int out_size, void* d_ws, size_t ws_size,
                              hipStream_t stream) {
  const float* X     = (const float*)d_in[0];
  const float* means = (const float*)d_in[1];
  const float* chols = (const float*)d_in[2];
  const float* wts   = (const float*)d_in[3];
  float* out = (float*)d_out;
  char* ws = (char*)d_ws;
  uint4*    Afrag    = (uint4*)ws;                // 98304
  float*    Kc       = (float*)(ws + 98304);      // 128   -> 98432
  float*    Sg       = (float*)(ws + 98432);      // 128   -> 98560
  double*   zterm    = (double*)(ws + 98560);     // 8192  -> 106752
  double*   partials = (double*)(ws + 106752);    // 4096  -> 110848
  unsigned* ticket   = (unsigned*)(ws + 110848);  // 4     -> 110852

  setup_kernel<<<8, 256, 0, stream>>>(means, chols, wts, Afrag, Kc, Sg, ticket);
  work_kernel<<<GRID, 256, 0, stream>>>(X, means, chols, wts, Afrag, Kc, Sg,
                                        zterm, partials, ticket, out);
}

// Round 11
// 129.177 us; speedup vs baseline: 1.7430x; 1.0287x over previous
//
#include <hip/hip_runtime.h>
#include <math.h>

#define NPTS  131072
#define NPTB  512          // point blocks: 256 thr = 4 waves x 2 ptsets x 32 pts
#define NPRB  256          // pair blocks: 4 pairs/block (1 per wave)
#define GRID  (NPTB + NPRB)
#define DLOG2PIF 58.8120661f
#define DLOG2PI  58.81206612467475
#define SHIFT 92.0f
#define NEGHALF_LOG2E -0.72134752044f
#define LOG2E 1.44269504089f

typedef __attribute__((ext_vector_type(8)))  short short8;
typedef __attribute__((ext_vector_type(16))) float f32x16;

static __device__ __forceinline__ unsigned bfh(float f) {    // fp32 -> bf16 bits (RNE)
  unsigned u = __float_as_uint(f);
  return (u + 0x7FFFu + ((u >> 16) & 1u)) >> 16;
}
static __device__ __forceinline__ float bfhf(float f) {
  return __uint_as_float(bfh(f) << 16);
}
static __device__ __forceinline__ short8 mk_a2(unsigned w) { // {w,0,0,0} as short8
  int4 t = {(int)w, 0, 0, 0};
  return __builtin_bit_cast(short8, t);
}

// ===== setup: 8 blocks x 256 thr; wave wv handles cluster blockIdx*4+wv ============
// Sigma via 6 split-bf16 MFMAs; register chol (rsqrt); LDS-rolled inversion with
// split accumulator (even/odd j) to halve the serial fma chain.
__global__ __launch_bounds__(256) void setup_kernel(
    const float* __restrict__ means, const float* __restrict__ chols,
    const float* __restrict__ wts,
    uint4* __restrict__ Afrag, float* __restrict__ Kc, float* __restrict__ Sg,
    unsigned* __restrict__ ticket)
{
  const int tid = threadIdx.x, wv = tid >> 6, lane = tid & 63;
  const int r = lane & 31, h = lane >> 5;
  const int k = blockIdx.x*4 + wv;
  __shared__ float SshA[4][1056];
  __shared__ float blsA[4][1056];
  float* Ssh = SshA[wv];
  float* bls = blsA[wv];
  if (blockIdx.x == 0 && tid == 0) *ticket = 0u;
  const float* cp = chols + (size_t)k*1024 + r*32;
  float4 fa = *(const float4*)(cp + h*8);
  float4 fb = *(const float4*)(cp + h*8 + 4);
  float4 fc = *(const float4*)(cp + 16 + h*8);
  float4 fd = *(const float4*)(cp + 16 + h*8 + 4);
  float v0[8] = {fa.x,fa.y,fa.z,fa.w,fb.x,fb.y,fb.z,fb.w};
  float v1[8] = {fc.x,fc.y,fc.z,fc.w,fd.x,fd.y,fd.z,fd.w};
  short8 hi0, hi1, lo0, lo1;
  #pragma unroll
  for (int j = 0; j < 8; j++) {
    hi0[j] = (short)bfh(v0[j]);  lo0[j] = (short)bfh(v0[j] - bfhf(v0[j]));
    hi1[j] = (short)bfh(v1[j]);  lo1[j] = (short)bfh(v1[j] - bfhf(v1[j]));
  }
  f32x16 acc = {};
  acc = __builtin_amdgcn_mfma_f32_32x32x16_bf16(hi0, hi0, acc, 0,0,0);
  acc = __builtin_amdgcn_mfma_f32_32x32x16_bf16(hi1, hi1, acc, 0,0,0);
  acc = __builtin_amdgcn_mfma_f32_32x32x16_bf16(hi0, lo0, acc, 0,0,0);
  acc = __builtin_amdgcn_mfma_f32_32x32x16_bf16(hi1, lo1, acc, 0,0,0);
  acc = __builtin_amdgcn_mfma_f32_32x32x16_bf16(lo0, hi0, acc, 0,0,0);
  acc = __builtin_amdgcn_mfma_f32_32x32x16_bf16(lo1, hi1, acc, 0,0,0);
  #pragma unroll
  for (int q = 0; q < 16; q++) {
    int row = (q & 3) + 8*(q >> 2) + 4*h;
    Ssh[row*33 + r] = acc[q] + ((row == r) ? 1.0f : 0.0f);
  }
  float a[32];
  #pragma unroll
  for (int j = 0; j < 32; j++) a[j] = Ssh[r*33 + j];   // lane r holds row r
  float ldsum = 0.0f;
  #pragma unroll
  for (int j = 0; j < 32; j++) {
    float dd = __shfl(a[j], j);
    float inv = __frsqrt_rn(dd);                       // 1/sqrt: kills sqrt->div chain
    float sq = dd * inv;
    ldsum += __logf(sq);
    float l = a[j] * inv;
    #pragma unroll
    for (int e = j+1; e < 32; e++) {
      float le = __shfl(l, e);
      a[e] = (r >= e) ? fmaf(-l, le, a[e]) : a[e];
    }
    a[j] = (r == j) ? sq : ((r > j) ? l : a[j]);
  }
  // L rows -> LDS (a[] dead afterwards; keeps register pressure low)
  #pragma unroll
  for (int j = 0; j < 32; j++) Ssh[r*33 + j] = a[j];
  // rolled column-parallel inversion, split accumulator halves the serial chain
  #pragma unroll 1
  for (int d = 0; d < 32; d++) {
    float s0 = (d == r) ? 1.0f : 0.0f, s1 = 0.0f;
    int j = 0;
    for (; j + 1 < d; j += 2) {
      s0 = fmaf(-Ssh[d*33 + j],     bls[j*33 + r],     s0);
      s1 = fmaf(-Ssh[d*33 + j + 1], bls[(j+1)*33 + r], s1);
    }
    if (j < d) s0 = fmaf(-Ssh[d*33 + j], bls[j*33 + r], s0);
    bls[d*33 + r] = (s0 + s1) / Ssh[d*33 + d];
  }
  float t0[8], t1[8];
  #pragma unroll
  for (int j = 0; j < 8; j++) {
    t0[j] = bls[r*33 + h*8 + j];
    t1[j] = bls[r*33 + 16 + h*8 + j];
  }
  uint4 s0 = make_uint4(bfh(t0[0])|(bfh(t0[1])<<16), bfh(t0[2])|(bfh(t0[3])<<16),
                        bfh(t0[4])|(bfh(t0[5])<<16), bfh(t0[6])|(bfh(t0[7])<<16));
  uint4 s1 = make_uint4(bfh(t1[0])|(bfh(t1[1])<<16), bfh(t1[2])|(bfh(t1[3])<<16),
                        bfh(t1[4])|(bfh(t1[5])<<16), bfh(t1[6])|(bfh(t1[7])<<16));
  float cvp = 0.0f;
  #pragma unroll
  for (int j = 0; j < 8; j++) {
    cvp = fmaf(t0[j], means[k*32 + h*8 + j], cvp);
    cvp = fmaf(t1[j], means[k*32 + 16 + h*8 + j], cvp);
  }
  float cv = cvp + __shfl_xor(cvp, 32);
  unsigned ch = bfh(cv) ^ 0x8000u;
  unsigned cl = bfh(cv - bfhf(cv)) ^ 0x8000u;
  uint4 s2 = make_uint4((h == 0) ? (ch | (cl<<16)) : 0u, 0u, 0u, 0u);
  Afrag[(k*3 + 0)*64 + lane] = s0;
  Afrag[(k*3 + 1)*64 + lane] = s1;
  Afrag[(k*3 + 2)*64 + lane] = s2;
  if (lane == 0) {
    float wk = wts[k];
    float ld2 = 2.0f*ldsum + DLOG2PIF;
    Kc[k] = LOG2E*(SHIFT - 0.5f*ld2) + log2f(fabsf(wk));
    Sg[k] = (wk < 0.0f) ? -1.0f : 1.0f;
  }
}

// ===== work: 512 point blocks + 256 pair blocks; fused last-block final ============
// Point role: 24.6 KB LDS (8 clusters/phase x 4 phases) -> 6 blocks/CU occupancy.
__global__ __launch_bounds__(256) void work_kernel(
    const float* __restrict__ X, const float* __restrict__ means,
    const float* __restrict__ chols, const float* __restrict__ wts,
    const uint4* __restrict__ Afrag, const float* __restrict__ Kc,
    const float* __restrict__ Sg,
    double* __restrict__ zterm, double* __restrict__ partials,
    unsigned* __restrict__ ticket, float* __restrict__ out)
{
  __shared__ __align__(16) char smem[24576];     // fsh (points) / Ssh (pairs, 16.9KB)
  __shared__ float K2sh[32], sksh[32];
  __shared__ double redd[4], redz[4];
  __shared__ unsigned lastFlag;
  const int tid = threadIdx.x, wv = tid >> 6, lane = tid & 63;
  const int r = lane & 31, h = lane >> 5;
  if (blockIdx.x < NPTB) {
    // ================= points: 4 waves x 2 ptsets x 32 pts =================
    uint4* fsh = (uint4*)smem;
    const unsigned* fshw = (const unsigned*)smem;
    if (tid < 32) { K2sh[tid] = Kc[tid]; sksh[tid] = Sg[tid]; }
    const int n0 = blockIdx.x*256 + wv*64 + r;   // set0; set1 = n0+32
    short8 xh00, xh01, xh10, xh11, x2c;
    {
      const float* xp0 = X + (size_t)n0*32;
      const float* xp1 = X + (size_t)(n0+32)*32;
      float4 fa = *(const float4*)(xp0 + h*8);
      float4 fb = *(const float4*)(xp0 + h*8 + 4);
      float4 fc = *(const float4*)(xp0 + 16 + h*8);
      float4 fd = *(const float4*)(xp0 + 16 + h*8 + 4);
      float4 ga = *(const float4*)(xp1 + h*8);
      float4 gb = *(const float4*)(xp1 + h*8 + 4);
      float4 gc = *(const float4*)(xp1 + 16 + h*8);
      float4 gd = *(const float4*)(xp1 + 16 + h*8 + 4);
      float v00[8] = {fa.x,fa.y,fa.z,fa.w,fb.x,fb.y,fb.z,fb.w};
      float v01[8] = {fc.x,fc.y,fc.z,fc.w,fd.x,fd.y,fd.z,fd.w};
      float v10[8] = {ga.x,ga.y,ga.z,ga.w,gb.x,gb.y,gb.z,gb.w};
      float v11[8] = {gc.x,gc.y,gc.z,gc.w,gd.x,gd.y,gd.z,gd.w};
      #pragma unroll
      for (int j = 0; j < 8; j++) {
        xh00[j] = (short)bfh(v00[j]);  xh01[j] = (short)bfh(v01[j]);
        xh10[j] = (short)bfh(v10[j]);  xh11[j] = (short)bfh(v11[j]);
        x2c[j] = 0;
      }
      if (h == 0) { x2c[0] = (short)0x3F80; x2c[1] = (short)0x3F80; }
    }
    float sF0 = 0.0f, sF1 = 0.0f;
    #pragma unroll 1
    for (int ph = 0; ph < 4; ph++) {
      __syncthreads();
      const uint4* src = Afrag + ph*1536;
      #pragma unroll
      for (int t = tid; t < 1536; t += 256) fsh[t] = src[t];
      __syncthreads();
      #pragma unroll 4
      for (int kk = 0; kk < 8; kk++) {
        const short8* fp = (const short8*)(fsh + kk*192);
        short8 a0 = fp[lane], a1 = fp[64+lane];
        short8 a2 = mk_a2(fshw[(kk*192 + 128 + lane)*4]);   // only word0 nonzero
        const int kidx = ph*8 + kk;
        const float Kk = K2sh[kidx], sk = sksh[kidx];
        f32x16 acc0 = {}, acc1 = {};
        acc0 = __builtin_amdgcn_mfma_f32_32x32x16_bf16(a0, xh00, acc0, 0,0,0);
        acc0 = __builtin_amdgcn_mfma_f32_32x32x16_bf16(a1, xh01, acc0, 0,0,0);
        acc0 = __builtin_amdgcn_mfma_f32_32x32x16_bf16(a2, x2c,  acc0, 0,0,0);
        acc1 = __builtin_amdgcn_mfma_f32_32x32x16_bf16(a0, xh10, acc1, 0,0,0);
        acc1 = __builtin_amdgcn_mfma_f32_32x32x16_bf16(a1, xh11, acc1, 0,0,0);
        acc1 = __builtin_amdgcn_mfma_f32_32x32x16_bf16(a2, x2c,  acc1, 0,0,0);
        float m0a=0.f, m0b=0.f, m1a=0.f, m1b=0.f;
        #pragma unroll
        for (int q = 0; q < 8; q++) {
          m0a = fmaf(acc0[q],   acc0[q],   m0a);
          m0b = fmaf(acc0[q+8], acc0[q+8], m0b);
          m1a = fmaf(acc1[q],   acc1[q],   m1a);
          m1b = fmaf(acc1[q+8], acc1[q+8], m1b);
        }
        float m0 = m0a + m0b, m1 = m1a + m1b;
        m0 += __shfl_xor(m0, 32);
        m1 += __shfl_xor(m1, 32);
        sF0 = fmaf(sk, exp2f(fmaf(m0, NEGHALF_LOG2E, Kk)), sF0);
        sF1 = fmaf(sk, exp2f(fmaf(m1, NEGHALF_LOG2E, Kk)), sF1);
      }
    }
    // T-partial: plain fp64 sum of sF^2 (log-shift folded: T = sum * e^{-184})
    double Tp = (double)sF0*(double)sF0 + (double)sF1*(double)sF1;
    if (lane >= 32) Tp = 0.0;                    // upper halves duplicate
    #pragma unroll
    for (int off = 32; off > 0; off >>= 1) Tp += __shfl_down(Tp, off);
    if (lane == 0) redd[wv] = Tp;
    __syncthreads();
    if (tid == 0) partials[blockIdx.x] = redd[0] + redd[1] + redd[2] + redd[3];
  } else {
    // ================= pairs: 1 pair per wave, from chols ==================
    float* Ssh = (float*)smem + wv*1056;
    const int pid = (blockIdx.x - NPTB)*4 + wv, pi = pid >> 5, pj = pid & 31;
    const float* cpi = chols + (size_t)pi*1024 + r*32;
    const float* cpj = chols + (size_t)pj*1024 + r*32;
    float4 ia = *(const float4*)(cpi + h*8);
    float4 ib = *(const float4*)(cpi + h*8 + 4);
    float4 ic = *(const float4*)(cpi + 16 + h*8);
    float4 id = *(const float4*)(cpi + 16 + h*8 + 4);
    float4 ja = *(const float4*)(cpj + h*8);
    float4 jb = *(const float4*)(cpj + h*8 + 4);
    float4 jc = *(const float4*)(cpj + 16 + h*8);
    float4 jd = *(const float4*)(cpj + 16 + h*8 + 4);
    float vi0[8] = {ia.x,ia.y,ia.z,ia.w,ib.x,ib.y,ib.z,ib.w};
    float vi1[8] = {ic.x,ic.y,ic.z,ic.w,id.x,id.y,id.z,id.w};
    float vj0[8] = {ja.x,ja.y,ja.z,ja.w,jb.x,jb.y,jb.z,jb.w};
    float vj1[8] = {jc.x,jc.y,jc.z,jc.w,jd.x,jd.y,jd.z,jd.w};
    short8 I0h,I0l,I1h,I1l,J0h,J0l,J1h,J1l;
    #pragma unroll
    for (int j = 0; j < 8; j++) {
      I0h[j]=(short)bfh(vi0[j]); I0l[j]=(short)bfh(vi0[j]-bfhf(vi0[j]));
      I1h[j]=(short)bfh(vi1[j]); I1l[j]=(short)bfh(vi1[j]-bfhf(vi1[j]));
      J0h[j]=(short)bfh(vj0[j]); J0l[j]=(short)bfh(vj0[j]-bfhf(vj0[j]));
      J1h[j]=(short)bfh(vj1[j]); J1l[j]=(short)bfh(vj1[j]-bfhf(vj1[j]));
    }
    f32x16 pacc = {};
    pacc = __builtin_amdgcn_mfma_f32_32x32x16_bf16(I0h, I0h, pacc, 0,0,0);
    pacc = __builtin_amdgcn_mfma_f32_32x32x16_bf16(I1h, I1h, pacc, 0,0,0);
    pacc = __builtin_amdgcn_mfma_f32_32x32x16_bf16(I0h, I0l, pacc, 0,0,0);
    pacc = __builtin_amdgcn_mfma_f32_32x32x16_bf16(I1h, I1l, pacc, 0,0,0);
    pacc = __builtin_amdgcn_mfma_f32_32x32x16_bf16(I0l, I0h, pacc, 0,0,0);
    pacc = __builtin_amdgcn_mfma_f32_32x32x16_bf16(I1l, I1h, pacc, 0,0,0);
    pacc = __builtin_amdgcn_mfma_f32_32x32x16_bf16(J0h, J0h, pacc, 0,0,0);
    pacc = __builtin_amdgcn_mfma_f32_32x32x16_bf16(J1h, J1h, pacc, 0,0,0);
    pacc = __builtin_amdgcn_mfma_f32_32x32x16_bf16(J0h, J0l, pacc, 0,0,0);
    pacc = __builtin_amdgcn_mfma_f32_32x32x16_bf16(J1h, J1l, pacc, 0,0,0);
    pacc = __builtin_amdgcn_mfma_f32_32x32x16_bf16(J0l, J0h, pacc, 0,0,0);
    pacc = __builtin_amdgcn_mfma_f32_32x32x16_bf16(J1l, J1h, pacc, 0,0,0);
    #pragma unroll
    for (int q = 0; q < 16; q++) {
      int row = (q & 3) + 8*(q >> 2) + 4*h;
      Ssh[row*33 + r] = pacc[q] + ((row == r) ? 2.0f : 0.0f);
    }
    float a[32];
    #pragma unroll
    for (int j = 0; j < 32; j++) a[j] = Ssh[r*33 + j];
    #pragma unroll
    for (int j = 0; j < 32; j++) {
      float dd = __shfl(a[j], j);
      float inv = __frsqrt_rn(dd);
      float sq = dd * inv;
      float l = a[j] * inv;
      #pragma unroll
      for (int e = j+1; e < 32; e++) {
        float le = __shfl(l, e);
        a[e] = (r >= e) ? fmaf(-l, le, a[e]) : a[e];
      }
      a[j] = (r == j) ? sq : ((r > j) ? l : a[j]);
    }
    float acc2 = means[pi*32 + r] - means[pj*32 + r];
    float maha = 0.0f, ldsum = 0.0f;
    #pragma unroll
    for (int d = 0; d < 32; d++) {
      float dd = __shfl(a[d], d);
      float yd = __shfl(acc2, d) / dd;
      maha = fmaf(yd, yd, maha);
      ldsum += __logf(dd);
      acc2 = (r > d) ? fmaf(-a[d], yd, acc2) : acc2;
    }
    if (lane == 0) {
      double vd = -0.5 * ((double)maha + 2.0*(double)ldsum + DLOG2PI);
      zterm[pid] = (double)wts[pi] * (double)wts[pj] * exp(vd);
    }
  }
  // ================= end-of-kernel ticket + fused final ====================
  __syncthreads();
  if (tid == 0) {
    __threadfence();
    lastFlag = (atomicAdd(ticket, 1u) == GRID - 1) ? 1u : 0u;
  }
  __syncthreads();
  if (lastFlag) {
    __threadfence();
    double t = 0.0, z = 0.0;
    for (int p = tid; p < NPTB; p += 256) t += partials[p];
    for (int p = tid; p < 1024; p += 256) z += zterm[p];
    #pragma unroll
    for (int off = 32; off > 0; off >>= 1) {
      t += __shfl_down(t, off);
      z += __shfl_down(z, off);
    }
    if (lane == 0) { redd[wv] = t; redz[wv] = z; }
    __syncthreads();
    if (tid == 0) {
      t = redd[0] + redd[1] + redd[2] + redd[3];
      z = redz[0] + redz[1] + redz[2] + redz[3];
      double logT = log(t) - 2.0*(double)SHIFT;
      double logz = log(z);
      out[0] = (float)((logz - logT) / (double)NPTS);
    }
  }
}

extern "C" void kernel_launch(void* const* d_in, const int* in_sizes, int n_in,
                              void* d_out, int out_size, void* d_ws, size_t ws_size,
                              hipStream_t stream) {
  const float* X     = (const float*)d_in[0];
  const float* means = (const float*)d_in[1];
  const float* chols = (const float*)d_in[2];
  const float* wts   = (const float*)d_in[3];
  float* out = (float*)d_out;
  char* ws = (char*)d_ws;
  uint4*    Afrag    = (uint4*)ws;                // 98304
  float*    Kc       = (float*)(ws + 98304);      // 128   -> 98432
  float*    Sg       = (float*)(ws + 98432);      // 128   -> 98560
  double*   zterm    = (double*)(ws + 98560);     // 8192  -> 106752
  double*   partials = (double*)(ws + 106752);    // 4096  -> 110848
  unsigned* ticket   = (unsigned*)(ws + 110848);  // 4     -> 110852

  setup_kernel<<<8, 256, 0, stream>>>(means, chols, wts, Afrag, Kc, Sg, ticket);
  work_kernel<<<GRID, 256, 0, stream>>>(X, means, chols, wts, Afrag, Kc, Sg,
                                        zterm, partials, ticket, out);
}